// Round 12
// baseline (329.265 us; speedup 1.0000x reference)
//
#include <hip/hip_runtime.h>
#include <hip/hip_bf16.h>

#define HW 4096
#define CCH 512
#define SDIM 64
#define BDIM 8

typedef __attribute__((ext_vector_type(8))) short short8;
typedef __attribute__((ext_vector_type(4))) float f32x4;

static __device__ __forceinline__ ushort f2bf(float f) {
  __hip_bfloat16 h = __float2bfloat16(f);  // RNE
  return *reinterpret_cast<ushort*>(&h);
}
static __device__ __forceinline__ float bf2f(ushort u) {
  union { unsigned int u32; float f; } c;
  c.u32 = ((unsigned int)u) << 16;
  return c.f;
}

// async global->LDS DMA: lane contributes 16B; LDS dest = uniform base + lane*16
static __device__ __forceinline__ void gll16(const float* g, float* lds_base) {
  __builtin_amdgcn_global_load_lds(
      (const __attribute__((address_space(1))) unsigned int*)g,
      (__attribute__((address_space(3))) unsigned int*)lds_base, 16, 0, 0);
}

// K0: split the three projection weights into bf16 hi/mid/lo triples [br][s][c]
__global__ __launch_bounds__(256) void prep_kernel(const float* __restrict__ Wq,
                                                   const float* __restrict__ Wk,
                                                   const float* __restrict__ Wv,
                                                   ushort* __restrict__ whi,
                                                   ushort* __restrict__ wmid,
                                                   ushort* __restrict__ wlo) {
  const float* W = blockIdx.y == 0 ? Wq : (blockIdx.y == 1 ? Wk : Wv);
  const int idx = blockIdx.x * 1024 + threadIdx.x * 4;
  float4 f = *reinterpret_cast<const float4*>(&W[idx]);
  ushort4 h, m, l;
  float r, r2;
  h.x = f2bf(f.x); r = f.x - bf2f(h.x); m.x = f2bf(r); r2 = r - bf2f(m.x); l.x = f2bf(r2);
  h.y = f2bf(f.y); r = f.y - bf2f(h.y); m.y = f2bf(r); r2 = r - bf2f(m.y); l.y = f2bf(r2);
  h.z = f2bf(f.z); r = f.z - bf2f(h.z); m.z = f2bf(r); r2 = r - bf2f(m.z); l.z = f2bf(r2);
  h.w = f2bf(f.w); r = f.w - bf2f(h.w); m.w = f2bf(r); r2 = r - bf2f(m.w); l.w = f2bf(r2);
  const size_t o = (size_t)blockIdx.y * (SDIM * CCH) + idx;
  *reinterpret_cast<ushort4*>(&whi[o])  = h;
  *reinterpret_cast<ushort4*>(&wmid[o]) = m;
  *reinterpret_cast<ushort4*>(&wlo[o])  = l;
}

// K1: 3-way-split bf16 MFMA projection, Ootomo two-accumulator.
//   M=256 hw tile, 8 waves, chunk=32c. Block-cooperative staging: each
//   global_load_lds reads ONE FULL c-row slice = 1 KB CONTIGUOUS (DRAM-burst
//   friendly; the 16KB c-stride only appears BETWEEN 1KB transactions).
//   Raw s_barrier (no vmcnt0 drain); weights loaded BEFORE the DMA prefetch so
//   vmcnt(4) leaves only next chunk's DMAs in flight.
//   ap[br][hw][b][s] = sum_c x_br[b][c][hw] * w_br[s][c]
__global__ __launch_bounds__(512, 2) void proj_mfma_kernel(const float* __restrict__ q,
                                                           const float* __restrict__ k,
                                                           const float* __restrict__ v,
                                                           const ushort* __restrict__ whi,
                                                           const ushort* __restrict__ wmid,
                                                           const ushort* __restrict__ wlo,
                                                           float* __restrict__ ap) {
  __shared__ float Xs[2][32 * 256];  // 64 KB: [buf][c_local*256 + hw']
  const int mt = blockIdx.x;   // 16 tiles of 256 hw
  const int b = blockIdx.y;
  const int br = blockIdx.z;
  const float* x = br == 0 ? q : (br == 1 ? k : v);
  const ushort* wh = whi + (size_t)br * SDIM * CCH;
  const ushort* wm = wmid + (size_t)br * SDIM * CCH;
  const ushort* wl = wlo + (size_t)br * SDIM * CCH;
  float* apo = ap + (size_t)br * HW * 512;
  const int hw0 = mt * 256;
  const int tid = threadIdx.x;
  const int l = tid & 63;
  const int w = tid >> 6;          // wave 0..7 -> 32-hw strip
  const int w4 = w * 4;            // staging: wave covers 4 c-rows per chunk
  const int row16 = l & 15;
  const int kgrp = l >> 4;
  const float* xb = x + (size_t)b * CCH * HW + hw0 + l * 4;  // lane's 16B slot in a c-row

  f32x4 acc_hi[2][4] = {};
  f32x4 acc_co[2][4] = {};

  // prologue: stage chunk 0
#pragma unroll
  for (int j = 0; j < 4; ++j)
    gll16(xb + (size_t)(w4 + j) * HW, &Xs[0][(w4 + j) * 256]);

  for (int ci = 0; ci < 16; ++ci) {
    // weight fragments for THIS chunk — issued before the DMA prefetch
    short8 bh[4], bm[4], bl[4];
#pragma unroll
    for (int nf = 0; nf < 4; ++nf) {
      const size_t off = (size_t)(nf * 16 + row16) * CCH + ci * 32 + kgrp * 8;
      bh[nf] = *reinterpret_cast<const short8*>(&wh[off]);
      bm[nf] = *reinterpret_cast<const short8*>(&wm[off]);
      bl[nf] = *reinterpret_cast<const short8*>(&wl[off]);
    }
    __builtin_amdgcn_sched_barrier(0);
    if (ci < 15) {
#pragma unroll
      for (int j = 0; j < 4; ++j)
        gll16(xb + (size_t)((ci + 1) * 32 + w4 + j) * HW, &Xs[(ci + 1) & 1][(w4 + j) * 256]);
    }
    __builtin_amdgcn_sched_barrier(0);
    if (ci < 15) {
      asm volatile("s_waitcnt vmcnt(4)" ::: "memory");  // this chunk's DMAs + weights done; next chunk in flight
    } else {
      asm volatile("s_waitcnt vmcnt(0)" ::: "memory");
    }
    __builtin_amdgcn_sched_barrier(0);
    __builtin_amdgcn_s_barrier();            // all waves' chunk-ci rows landed
    __builtin_amdgcn_sched_barrier(0);

    const float* lw = &Xs[ci & 1][0];
#pragma unroll
    for (int mf = 0; mf < 2; ++mf) {
      ushort th[8], tm[8], tl[8];
#pragma unroll
      for (int i = 0; i < 8; ++i) {
        const float f = lw[(kgrp * 8 + i) * 256 + w * 32 + mf * 16 + row16];
        const ushort h = f2bf(f);
        const float r = f - bf2f(h);
        const ushort mv = f2bf(r);
        const float r2 = r - bf2f(mv);
        th[i] = h; tm[i] = mv; tl[i] = f2bf(r2);
      }
      const short8 ah = *reinterpret_cast<const short8*>(th);
      const short8 am = *reinterpret_cast<const short8*>(tm);
      const short8 al = *reinterpret_cast<const short8*>(tl);
#pragma unroll
      for (int nf = 0; nf < 4; ++nf) {
        acc_hi[mf][nf] = __builtin_amdgcn_mfma_f32_16x16x32_bf16(ah, bh[nf], acc_hi[mf][nf], 0, 0, 0);
        acc_co[mf][nf] = __builtin_amdgcn_mfma_f32_16x16x32_bf16(ah, bm[nf], acc_co[mf][nf], 0, 0, 0);
        acc_co[mf][nf] = __builtin_amdgcn_mfma_f32_16x16x32_bf16(am, bh[nf], acc_co[mf][nf], 0, 0, 0);
        acc_co[mf][nf] = __builtin_amdgcn_mfma_f32_16x16x32_bf16(am, bm[nf], acc_co[mf][nf], 0, 0, 0);
        acc_co[mf][nf] = __builtin_amdgcn_mfma_f32_16x16x32_bf16(ah, bl[nf], acc_co[mf][nf], 0, 0, 0);
        acc_co[mf][nf] = __builtin_amdgcn_mfma_f32_16x16x32_bf16(al, bh[nf], acc_co[mf][nf], 0, 0, 0);
        acc_co[mf][nf] = __builtin_amdgcn_mfma_f32_16x16x32_bf16(am, bl[nf], acc_co[mf][nf], 0, 0, 0);
        acc_co[mf][nf] = __builtin_amdgcn_mfma_f32_16x16x32_bf16(al, bm[nf], acc_co[mf][nf], 0, 0, 0);
      }
    }
    __builtin_amdgcn_sched_barrier(0);
    __builtin_amdgcn_s_barrier();            // all waves done reading buf before it's overwritten
    __builtin_amdgcn_sched_barrier(0);
  }

#pragma unroll
  for (int mf = 0; mf < 2; ++mf)
#pragma unroll
    for (int nf = 0; nf < 4; ++nf)
#pragma unroll
      for (int r = 0; r < 4; ++r) {
        const int m = hw0 + w * 32 + mf * 16 + kgrp * 4 + r;
        apo[(size_t)m * 512 + b * 64 + nf * 16 + row16] = acc_hi[mf][nf][r] + acc_co[mf][nf][r];
      }
}

// K2: rD[br][h][s][t] = 1 / sum_w exp( sum_b A[h,w,b,s]*B[h,w,b,t] )
//   s split across 4 blocks (grid 768 = 3/CU); same FMA order -> bit-identical rD
__global__ __launch_bounds__(512) void denom_kernel(const float* __restrict__ ap,
                                                    float* __restrict__ rD) {
  __shared__ float As[8 * 16];   // [b][s_local]
  __shared__ float Bs[8 * 64];   // [b][t]
  const int h = blockIdx.x, br = blockIdx.y, sq = blockIdx.z;
  const float* A  = ap + ((size_t)br * HW + (size_t)h * 64) * (BDIM * SDIM);
  const float* Bp = ap + ((size_t)((br + 1) % 3) * HW + (size_t)h * 64) * (BDIM * SDIM);
  const int tid = threadIdx.x;
  const int t = tid & 63;
  const int sg = tid >> 6;  // 0..7, each covers 2 s
  float D[2] = {};
  for (int w = 0; w < 64; ++w) {
    __syncthreads();
    if (tid < 128) As[tid] = A[w * 512 + (tid >> 4) * 64 + sq * 16 + (tid & 15)];
    Bs[tid] = Bp[w * 512 + tid];
    __syncthreads();
    float bv[8];
#pragma unroll
    for (int b = 0; b < 8; ++b) bv[b] = Bs[b * 64 + t];
#pragma unroll
    for (int j = 0; j < 2; ++j) {
      const int sl = sg * 2 + j;
      float m = 0.f;
#pragma unroll
      for (int b = 0; b < 8; ++b) m = fmaf(As[b * 16 + sl], bv[b], m);
      D[j] += __expf(m);
    }
  }
#pragma unroll
  for (int j = 0; j < 2; ++j)
    rD[((size_t)(br * 64 + h) * 64 + sq * 16 + sg * 2 + j) * 64 + t] = 1.0f / D[j];
}

// K3: on[br][hw][b][s] = o[s][b]/N[b], o = mtilde * C^T  (unchanged)
__global__ __launch_bounds__(256) void attn_kernel(const float* __restrict__ ap,
                                                   const float* __restrict__ rD,
                                                   float* __restrict__ on) {
  __shared__ float As[8 * 64], Bs[8 * 64], Cs[8 * 64];
  __shared__ float Ms[64 * 68];  // [s][t] padded
  const int wc = blockIdx.x, h = blockIdx.y, br = blockIdx.z;
  const float* A  = ap + ((size_t)br * HW + h * 64) * 512;
  const float* Bp = ap + ((size_t)((br + 1) % 3) * HW + h * 64) * 512;
  const float* Cp = ap + ((size_t)((br + 2) % 3) * HW + h * 64) * 512;
  const float* rDp = rD + (size_t)(br * 64 + h) * 4096;  // [s][t]
  const int tid = threadIdx.x;
  for (int w = wc * 8; w < wc * 8 + 8; ++w) {
    __syncthreads();
#pragma unroll
    for (int it = 0; it < 2; ++it) {
      int idx = it * 256 + tid;
      As[idx] = A[w * 512 + idx];
      Bs[idx] = Bp[w * 512 + idx];
      Cs[idx] = Cp[w * 512 + idx];
    }
    __syncthreads();
    {
      const int t = tid & 63, sg = tid >> 6;
      float bv[8];
#pragma unroll
      for (int b = 0; b < 8; ++b) bv[b] = Bs[b * 64 + t];
#pragma unroll
      for (int j = 0; j < 16; ++j) {
        int s = sg * 16 + j;
        float m = 0.f;
#pragma unroll
        for (int b = 0; b < 8; ++b) m = fmaf(As[b * 64 + s], bv[b], m);
        Ms[s * 68 + t] = __expf(m) * rDp[s * 64 + t];
      }
    }
    __syncthreads();
    const int s2 = tid & 63, bq = tid >> 6;
    float o0 = 0.f, o1 = 0.f;
#pragma unroll
    for (int tt = 0; tt < 64; tt += 4) {
      float4 mv = *reinterpret_cast<const float4*>(&Ms[s2 * 68 + tt]);
      float4 c0 = *reinterpret_cast<const float4*>(&Cs[bq * 64 + tt]);
      float4 c1 = *reinterpret_cast<const float4*>(&Cs[(bq + 4) * 64 + tt]);
      o0 = fmaf(mv.w, c0.w, fmaf(mv.z, c0.z, fmaf(mv.y, c0.y, fmaf(mv.x, c0.x, o0))));
      o1 = fmaf(mv.w, c1.w, fmaf(mv.z, c1.z, fmaf(mv.y, c1.y, fmaf(mv.x, c1.x, o1))));
    }
    float n0 = o0, n1 = o1;
#pragma unroll
    for (int off = 32; off > 0; off >>= 1) {
      n0 += __shfl_xor(n0, off);
      n1 += __shfl_xor(n1, off);
    }
    const float r0 = 1.0f / n0, r1 = 1.0f / n1;
    const size_t ob = ((size_t)br * HW + h * 64 + w) * 512;
    on[ob + (size_t)bq * 64 + s2] = o0 * r0;
    on[ob + (size_t)(bq + 4) * 64 + s2] = o1 * r1;
  }
}

// K4: out[brb][c][hw] = sum_s on[br][hw][b][s] * wl[c][s]  (unchanged, MFMA role-swap)
__global__ __launch_bounds__(256) void out_kernel(const float* __restrict__ on,
                                                  const float* __restrict__ wl,
                                                  float* __restrict__ out) {
  __shared__ float Os[128 * 68];  // [hw_local][s] pad 68
  const int hwt = blockIdx.x;     // 32 tiles of 128 hw
  const int brb = blockIdx.y;     // 0..23
  const int br = brb >> 3, b = brb & 7;
  const int hw0 = hwt * 128;
  const int tid = threadIdx.x;
  const int l = tid & 63;
  const int wv = tid >> 6;        // wave 0..3 -> hw strip of 32
  const int l15 = l & 15;
  const int kgrp = l >> 4;

  {
    const int row = tid >> 4;
    const int s4 = (tid & 15) * 4;
#pragma unroll
    for (int it = 0; it < 8; ++it) {
      const int r = row + it * 16;
      *reinterpret_cast<float4*>(&Os[r * 68 + s4]) =
          *reinterpret_cast<const float4*>(&on[((size_t)(br * HW + hw0 + r) * 8 + b) * 64 + s4]);
    }
  }
  __syncthreads();

  short8 onh[2][2], onl[2][2];
#pragma unroll
  for (int nf = 0; nf < 2; ++nf)
#pragma unroll
    for (int ks = 0; ks < 2; ++ks) {
      const int row = wv * 32 + nf * 16 + l15;
      const float* p = &Os[row * 68 + ks * 32 + kgrp * 8];
      ushort th[8], tl[8];
#pragma unroll
      for (int i = 0; i < 8; ++i) {
        const float f = p[i];
        const ushort h = f2bf(f);
        th[i] = h;
        tl[i] = f2bf(f - bf2f(h));
      }
      onh[nf][ks] = *reinterpret_cast<const short8*>(th);
      onl[nf][ks] = *reinterpret_cast<const short8*>(tl);
    }

  for (int mf = 0; mf < 32; ++mf) {
    f32x4 acc[2] = {};
#pragma unroll
    for (int ks = 0; ks < 2; ++ks) {
      const float* wp = &wl[(size_t)(mf * 16 + l15) * 64 + ks * 32 + kgrp * 8];
      ushort th[8], tl[8];
#pragma unroll
      for (int i = 0; i < 8; ++i) {
        const float f = wp[i];
        const ushort h = f2bf(f);
        th[i] = h;
        tl[i] = f2bf(f - bf2f(h));
      }
      const short8 wh8 = *reinterpret_cast<const short8*>(th);
      const short8 wl8 = *reinterpret_cast<const short8*>(tl);
#pragma unroll
      for (int nf = 0; nf < 2; ++nf) {
        acc[nf] = __builtin_amdgcn_mfma_f32_16x16x32_bf16(wh8, onh[nf][ks], acc[nf], 0, 0, 0);
        acc[nf] = __builtin_amdgcn_mfma_f32_16x16x32_bf16(wh8, onl[nf][ks], acc[nf], 0, 0, 0);
        acc[nf] = __builtin_amdgcn_mfma_f32_16x16x32_bf16(wl8, onh[nf][ks], acc[nf], 0, 0, 0);
      }
    }
#pragma unroll
    for (int nf = 0; nf < 2; ++nf)
#pragma unroll
      for (int r = 0; r < 4; ++r) {
        const int cc = mf * 16 + kgrp * 4 + r;
        out[(size_t)(brb * 512 + cc) * HW + hw0 + wv * 32 + nf * 16 + l15] = acc[nf][r];
      }
  }
}

extern "C" void kernel_launch(void* const* d_in, const int* in_sizes, int n_in,
                              void* d_out, int out_size, void* d_ws, size_t ws_size,
                              hipStream_t stream) {
  const float* q  = (const float*)d_in[0];
  const float* k  = (const float*)d_in[1];
  const float* v  = (const float*)d_in[2];
  const float* Wq = (const float*)d_in[3];
  const float* Wk = (const float*)d_in[4];
  const float* Wv = (const float*)d_in[5];
  const float* Wl = (const float*)d_in[6];
  float* out = (float*)d_out;

  float* ap = (float*)d_ws;                         // 3*HW*B*S floats = 25.2 MB
  float* rD = ap + (size_t)3 * HW * 512;            // 3*64*64*64 floats = 3.1 MB
  float* on = rD + (size_t)3 * 64 * 64 * 64;        // 3*HW*B*S floats = 25.2 MB
  ushort* whi  = (ushort*)rD;                       // 192 KB, consumed before denom overwrites rD
  ushort* wmid = whi + (size_t)3 * SDIM * CCH;
  ushort* wlo  = wmid + (size_t)3 * SDIM * CCH;

  prep_kernel<<<dim3(32, 3), 256, 0, stream>>>(Wq, Wk, Wv, whi, wmid, wlo);
  proj_mfma_kernel<<<dim3(16, 8, 3), 512, 0, stream>>>(q, k, v, whi, wmid, wlo, ap);
  denom_kernel<<<dim3(64, 3, 4), 512, 0, stream>>>(ap, rD);
  attn_kernel<<<dim3(8, 64, 3), 256, 0, stream>>>(ap, rD, on);
  out_kernel<<<dim3(32, 24), 256, 0, stream>>>(on, Wl, out);
}

// Round 13
// 290.885 us; speedup vs baseline: 1.1319x; 1.1319x over previous
//
#include <hip/hip_runtime.h>
#include <hip/hip_bf16.h>

#define HW 4096
#define CCH 512
#define SDIM 64
#define BDIM 8

typedef __attribute__((ext_vector_type(8))) short short8;
typedef __attribute__((ext_vector_type(4))) float f32x4;

static __device__ __forceinline__ ushort f2bf(float f) {
  __hip_bfloat16 h = __float2bfloat16(f);  // RNE
  return *reinterpret_cast<ushort*>(&h);
}
static __device__ __forceinline__ float bf2f(ushort u) {
  union { unsigned int u32; float f; } c;
  c.u32 = ((unsigned int)u) << 16;
  return c.f;
}

// K0: split the three projection weights into bf16 hi/mid/lo triples [br][s][c]
__global__ __launch_bounds__(256) void prep_kernel(const float* __restrict__ Wq,
                                                   const float* __restrict__ Wk,
                                                   const float* __restrict__ Wv,
                                                   ushort* __restrict__ whi,
                                                   ushort* __restrict__ wmid,
                                                   ushort* __restrict__ wlo) {
  const float* W = blockIdx.y == 0 ? Wq : (blockIdx.y == 1 ? Wk : Wv);
  const int idx = blockIdx.x * 1024 + threadIdx.x * 4;
  float4 f = *reinterpret_cast<const float4*>(&W[idx]);
  ushort4 h, m, l;
  float r, r2;
  h.x = f2bf(f.x); r = f.x - bf2f(h.x); m.x = f2bf(r); r2 = r - bf2f(m.x); l.x = f2bf(r2);
  h.y = f2bf(f.y); r = f.y - bf2f(h.y); m.y = f2bf(r); r2 = r - bf2f(m.y); l.y = f2bf(r2);
  h.z = f2bf(f.z); r = f.z - bf2f(h.z); m.z = f2bf(r); r2 = r - bf2f(m.z); l.z = f2bf(r2);
  h.w = f2bf(f.w); r = f.w - bf2f(h.w); m.w = f2bf(r); r2 = r - bf2f(m.w); l.w = f2bf(r2);
  const size_t o = (size_t)blockIdx.y * (SDIM * CCH) + idx;
  *reinterpret_cast<ushort4*>(&whi[o])  = h;
  *reinterpret_cast<ushort4*>(&wmid[o]) = m;
  *reinterpret_cast<ushort4*>(&wlo[o])  = l;
}

// K1: 3-way-split bf16 MFMA projection, Ootomo two-accumulator, M=128.
//   Round-8 structure; staging upgraded to float4 (16B/lane) with XOR bank
//   swizzle (stride 128, hw ^= ((c>>3)&1)<<4): stage writes conflict-free,
//   compute reads 2-way (free). LDS 32 KB -> 5 blocks/CU.
//   ap[br][hw][b][s] = sum_c x_br[b][c][hw] * w_br[s][c]
__global__ __launch_bounds__(256) void proj_mfma_kernel(const float* __restrict__ q,
                                                        const float* __restrict__ k,
                                                        const float* __restrict__ v,
                                                        const ushort* __restrict__ whi,
                                                        const ushort* __restrict__ wmid,
                                                        const ushort* __restrict__ wlo,
                                                        float* __restrict__ ap) {
  __shared__ float Xs[64 * 128];   // 32 KB, XOR-swizzled [c][hw]
  const int mt = blockIdx.x;   // hw tile of 128
  const int b = blockIdx.y;
  const int br = blockIdx.z;
  const float* x = br == 0 ? q : (br == 1 ? k : v);
  const ushort* wh = whi + (size_t)br * SDIM * CCH;
  const ushort* wm = wmid + (size_t)br * SDIM * CCH;
  const ushort* wl = wlo + (size_t)br * SDIM * CCH;
  float* apo = ap + (size_t)br * HW * 512;
  const int hw0 = mt * 128;
  const int tid = threadIdx.x;
  const int l = tid & 63;
  const int wstrip = (tid >> 6) * 32;  // wave's 32-row m-strip
  const int row16 = l & 15;
  const int kgrp = l >> 4;

  f32x4 acc_hi[2][4] = {};
  f32x4 acc_co[2][4] = {};

  for (int c0 = 0; c0 < CCH; c0 += 64) {
    __syncthreads();
    // stage [64 c][128 hw] f32 via float4 (16B/lane), XOR swizzle on hw
#pragma unroll
    for (int it = 0; it < 8; ++it) {
      const int fidx = (it * 256 + tid) * 4;
      const int cc = fidx >> 7;
      const int hwi = fidx & 127;
      const int hws = hwi ^ (((cc >> 3) & 1) << 4);
      *reinterpret_cast<float4*>(&Xs[cc * 128 + hws]) =
          *reinterpret_cast<const float4*>(&x[(size_t)(b * CCH + c0 + cc) * HW + hw0 + hwi]);
    }
    __syncthreads();
#pragma unroll
    for (int ks = 0; ks < 2; ++ks) {
      short8 bh[4], bm[4], bl[4];
#pragma unroll
      for (int nf = 0; nf < 4; ++nf) {
        const size_t off = (size_t)(nf * 16 + row16) * CCH + c0 + ks * 32 + kgrp * 8;
        bh[nf] = *reinterpret_cast<const short8*>(&wh[off]);
        bm[nf] = *reinterpret_cast<const short8*>(&wm[off]);
        bl[nf] = *reinterpret_cast<const short8*>(&wl[off]);
      }
#pragma unroll
      for (int mf = 0; mf < 2; ++mf) {
        const int rowA = wstrip + mf * 16 + row16;
        short8 ah, am, al;
        {
          ushort th[8], tm[8], tl[8];
#pragma unroll
          for (int i = 0; i < 8; ++i) {
            const int c = ks * 32 + kgrp * 8 + i;
            const float f = Xs[c * 128 + (rowA ^ (((c >> 3) & 1) << 4))];
            const ushort h = f2bf(f);
            const float r = f - bf2f(h);
            const ushort mmv = f2bf(r);
            const float r2 = r - bf2f(mmv);
            th[i] = h; tm[i] = mmv; tl[i] = f2bf(r2);
          }
          ah = *reinterpret_cast<const short8*>(th);
          am = *reinterpret_cast<const short8*>(tm);
          al = *reinterpret_cast<const short8*>(tl);
        }
#pragma unroll
        for (int nf = 0; nf < 4; ++nf) {
          // dominant term -> own accumulator
          acc_hi[mf][nf] = __builtin_amdgcn_mfma_f32_16x16x32_bf16(ah, bh[nf], acc_hi[mf][nf], 0, 0, 0);
          // correction terms -> separate accumulator (round at 2^-9 scale)
          acc_co[mf][nf] = __builtin_amdgcn_mfma_f32_16x16x32_bf16(ah, bm[nf], acc_co[mf][nf], 0, 0, 0);
          acc_co[mf][nf] = __builtin_amdgcn_mfma_f32_16x16x32_bf16(am, bh[nf], acc_co[mf][nf], 0, 0, 0);
          acc_co[mf][nf] = __builtin_amdgcn_mfma_f32_16x16x32_bf16(am, bm[nf], acc_co[mf][nf], 0, 0, 0);
          acc_co[mf][nf] = __builtin_amdgcn_mfma_f32_16x16x32_bf16(ah, bl[nf], acc_co[mf][nf], 0, 0, 0);
          acc_co[mf][nf] = __builtin_amdgcn_mfma_f32_16x16x32_bf16(al, bh[nf], acc_co[mf][nf], 0, 0, 0);
          acc_co[mf][nf] = __builtin_amdgcn_mfma_f32_16x16x32_bf16(am, bl[nf], acc_co[mf][nf], 0, 0, 0);
          acc_co[mf][nf] = __builtin_amdgcn_mfma_f32_16x16x32_bf16(al, bm[nf], acc_co[mf][nf], 0, 0, 0);
        }
      }
    }
  }
#pragma unroll
  for (int mf = 0; mf < 2; ++mf)
#pragma unroll
    for (int nf = 0; nf < 4; ++nf)
#pragma unroll
      for (int r = 0; r < 4; ++r) {
        const int m = hw0 + wstrip + mf * 16 + kgrp * 4 + r;
        apo[(size_t)m * 512 + b * 64 + nf * 16 + row16] = acc_hi[mf][nf][r] + acc_co[mf][nf][r];
      }
}

// K2: rD[br][h][s][t] = 1 / sum_w exp( sum_b A[h,w,b,s]*B[h,w,b,t] )
//   s split across 4 blocks (grid 768 = 3/CU); same FMA order -> bit-identical rD
__global__ __launch_bounds__(512) void denom_kernel(const float* __restrict__ ap,
                                                    float* __restrict__ rD) {
  __shared__ float As[8 * 16];   // [b][s_local]
  __shared__ float Bs[8 * 64];   // [b][t]
  const int h = blockIdx.x, br = blockIdx.y, sq = blockIdx.z;
  const float* A  = ap + ((size_t)br * HW + (size_t)h * 64) * (BDIM * SDIM);
  const float* Bp = ap + ((size_t)((br + 1) % 3) * HW + (size_t)h * 64) * (BDIM * SDIM);
  const int tid = threadIdx.x;
  const int t = tid & 63;
  const int sg = tid >> 6;  // 0..7, each covers 2 s
  float D[2] = {};
  for (int w = 0; w < 64; ++w) {
    __syncthreads();
    if (tid < 128) As[tid] = A[w * 512 + (tid >> 4) * 64 + sq * 16 + (tid & 15)];
    Bs[tid] = Bp[w * 512 + tid];
    __syncthreads();
    float bv[8];
#pragma unroll
    for (int b = 0; b < 8; ++b) bv[b] = Bs[b * 64 + t];
#pragma unroll
    for (int j = 0; j < 2; ++j) {
      const int sl = sg * 2 + j;
      float m = 0.f;
#pragma unroll
      for (int b = 0; b < 8; ++b) m = fmaf(As[b * 16 + sl], bv[b], m);
      D[j] += __expf(m);
    }
  }
#pragma unroll
  for (int j = 0; j < 2; ++j)
    rD[((size_t)(br * 64 + h) * 64 + sq * 16 + sg * 2 + j) * 64 + t] = 1.0f / D[j];
}

// K3: on[br][hw][b][s] = o[s][b]/N[b], o = mtilde * C^T  (unchanged)
__global__ __launch_bounds__(256) void attn_kernel(const float* __restrict__ ap,
                                                   const float* __restrict__ rD,
                                                   float* __restrict__ on) {
  __shared__ float As[8 * 64], Bs[8 * 64], Cs[8 * 64];
  __shared__ float Ms[64 * 68];  // [s][t] padded
  const int wc = blockIdx.x, h = blockIdx.y, br = blockIdx.z;
  const float* A  = ap + ((size_t)br * HW + h * 64) * 512;
  const float* Bp = ap + ((size_t)((br + 1) % 3) * HW + h * 64) * 512;
  const float* Cp = ap + ((size_t)((br + 2) % 3) * HW + h * 64) * 512;
  const float* rDp = rD + (size_t)(br * 64 + h) * 4096;  // [s][t]
  const int tid = threadIdx.x;
  for (int w = wc * 8; w < wc * 8 + 8; ++w) {
    __syncthreads();
#pragma unroll
    for (int it = 0; it < 2; ++it) {
      int idx = it * 256 + tid;
      As[idx] = A[w * 512 + idx];
      Bs[idx] = Bp[w * 512 + idx];
      Cs[idx] = Cp[w * 512 + idx];
    }
    __syncthreads();
    {
      const int t = tid & 63, sg = tid >> 6;
      float bv[8];
#pragma unroll
      for (int b = 0; b < 8; ++b) bv[b] = Bs[b * 64 + t];
#pragma unroll
      for (int j = 0; j < 16; ++j) {
        int s = sg * 16 + j;
        float m = 0.f;
#pragma unroll
        for (int b = 0; b < 8; ++b) m = fmaf(As[b * 64 + s], bv[b], m);
        Ms[s * 68 + t] = __expf(m) * rDp[s * 64 + t];
      }
    }
    __syncthreads();
    const int s2 = tid & 63, bq = tid >> 6;
    float o0 = 0.f, o1 = 0.f;
#pragma unroll
    for (int tt = 0; tt < 64; tt += 4) {
      float4 mv = *reinterpret_cast<const float4*>(&Ms[s2 * 68 + tt]);
      float4 c0 = *reinterpret_cast<const float4*>(&Cs[bq * 64 + tt]);
      float4 c1 = *reinterpret_cast<const float4*>(&Cs[(bq + 4) * 64 + tt]);
      o0 = fmaf(mv.w, c0.w, fmaf(mv.z, c0.z, fmaf(mv.y, c0.y, fmaf(mv.x, c0.x, o0))));
      o1 = fmaf(mv.w, c1.w, fmaf(mv.z, c1.z, fmaf(mv.y, c1.y, fmaf(mv.x, c1.x, o1))));
    }
    float n0 = o0, n1 = o1;
#pragma unroll
    for (int off = 32; off > 0; off >>= 1) {
      n0 += __shfl_xor(n0, off);
      n1 += __shfl_xor(n1, off);
    }
    const float r0 = 1.0f / n0, r1 = 1.0f / n1;
    const size_t ob = ((size_t)br * HW + h * 64 + w) * 512;
    on[ob + (size_t)bq * 64 + s2] = o0 * r0;
    on[ob + (size_t)(bq + 4) * 64 + s2] = o1 * r1;
  }
}

// K4: out[brb][c][hw] = sum_s on[br][hw][b][s] * wl[c][s]  (unchanged, MFMA role-swap)
__global__ __launch_bounds__(256) void out_kernel(const float* __restrict__ on,
                                                  const float* __restrict__ wl,
                                                  float* __restrict__ out) {
  __shared__ float Os[128 * 68];  // [hw_local][s] pad 68
  const int hwt = blockIdx.x;     // 32 tiles of 128 hw
  const int brb = blockIdx.y;     // 0..23
  const int br = brb >> 3, b = brb & 7;
  const int hw0 = hwt * 128;
  const int tid = threadIdx.x;
  const int l = tid & 63;
  const int wv = tid >> 6;        // wave 0..3 -> hw strip of 32
  const int l15 = l & 15;
  const int kgrp = l >> 4;

  {
    const int row = tid >> 4;
    const int s4 = (tid & 15) * 4;
#pragma unroll
    for (int it = 0; it < 8; ++it) {
      const int r = row + it * 16;
      *reinterpret_cast<float4*>(&Os[r * 68 + s4]) =
          *reinterpret_cast<const float4*>(&on[((size_t)(br * HW + hw0 + r) * 8 + b) * 64 + s4]);
    }
  }
  __syncthreads();

  short8 onh[2][2], onl[2][2];
#pragma unroll
  for (int nf = 0; nf < 2; ++nf)
#pragma unroll
    for (int ks = 0; ks < 2; ++ks) {
      const int row = wv * 32 + nf * 16 + l15;
      const float* p = &Os[row * 68 + ks * 32 + kgrp * 8];
      ushort th[8], tl[8];
#pragma unroll
      for (int i = 0; i < 8; ++i) {
        const float f = p[i];
        const ushort h = f2bf(f);
        th[i] = h;
        tl[i] = f2bf(f - bf2f(h));
      }
      onh[nf][ks] = *reinterpret_cast<const short8*>(th);
      onl[nf][ks] = *reinterpret_cast<const short8*>(tl);
    }

  for (int mf = 0; mf < 32; ++mf) {
    f32x4 acc[2] = {};
#pragma unroll
    for (int ks = 0; ks < 2; ++ks) {
      const float* wp = &wl[(size_t)(mf * 16 + l15) * 64 + ks * 32 + kgrp * 8];
      ushort th[8], tl[8];
#pragma unroll
      for (int i = 0; i < 8; ++i) {
        const float f = wp[i];
        const ushort h = f2bf(f);
        th[i] = h;
        tl[i] = f2bf(f - bf2f(h));
      }
      const short8 wh8 = *reinterpret_cast<const short8*>(th);
      const short8 wl8 = *reinterpret_cast<const short8*>(tl);
#pragma unroll
      for (int nf = 0; nf < 2; ++nf) {
        acc[nf] = __builtin_amdgcn_mfma_f32_16x16x32_bf16(wh8, onh[nf][ks], acc[nf], 0, 0, 0);
        acc[nf] = __builtin_amdgcn_mfma_f32_16x16x32_bf16(wh8, onl[nf][ks], acc[nf], 0, 0, 0);
        acc[nf] = __builtin_amdgcn_mfma_f32_16x16x32_bf16(wl8, onh[nf][ks], acc[nf], 0, 0, 0);
      }
    }
#pragma unroll
    for (int nf = 0; nf < 2; ++nf)
#pragma unroll
      for (int r = 0; r < 4; ++r) {
        const int cc = mf * 16 + kgrp * 4 + r;
        out[(size_t)(brb * 512 + cc) * HW + hw0 + wv * 32 + nf * 16 + l15] = acc[nf][r];
      }
  }
}

extern "C" void kernel_launch(void* const* d_in, const int* in_sizes, int n_in,
                              void* d_out, int out_size, void* d_ws, size_t ws_size,
                              hipStream_t stream) {
  const float* q  = (const float*)d_in[0];
  const float* k  = (const float*)d_in[1];
  const float* v  = (const float*)d_in[2];
  const float* Wq = (const float*)d_in[3];
  const float* Wk = (const float*)d_in[4];
  const float* Wv = (const float*)d_in[5];
  const float* Wl = (const float*)d_in[6];
  float* out = (float*)d_out;

  float* ap = (float*)d_ws;                         // 3*HW*B*S floats = 25.2 MB
  float* rD = ap + (size_t)3 * HW * 512;            // 3*64*64*64 floats = 3.1 MB
  float* on = rD + (size_t)3 * 64 * 64 * 64;        // 3*HW*B*S floats = 25.2 MB
  ushort* whi  = (ushort*)rD;                       // 192 KB, consumed before denom overwrites rD
  ushort* wmid = whi + (size_t)3 * SDIM * CCH;
  ushort* wlo  = wmid + (size_t)3 * SDIM * CCH;

  prep_kernel<<<dim3(32, 3), 256, 0, stream>>>(Wq, Wk, Wv, whi, wmid, wlo);
  proj_mfma_kernel<<<dim3(32, 8, 3), 256, 0, stream>>>(q, k, v, whi, wmid, wlo, ap);
  denom_kernel<<<dim3(64, 3, 4), 512, 0, stream>>>(ap, rD);
  attn_kernel<<<dim3(8, 64, 3), 256, 0, stream>>>(ap, rD, on);
  out_kernel<<<dim3(32, 24), 256, 0, stream>>>(on, Wl, out);
}

// Round 14
// 282.996 us; speedup vs baseline: 1.1635x; 1.0279x over previous
//
#include <hip/hip_runtime.h>
#include <hip/hip_bf16.h>

#define HW 4096
#define CCH 512
#define SDIM 64
#define BDIM 8

typedef __attribute__((ext_vector_type(8))) short short8;
typedef __attribute__((ext_vector_type(4))) float f32x4;

static __device__ __forceinline__ ushort f2bf(float f) {
  __hip_bfloat16 h = __float2bfloat16(f);  // RNE (cold paths only)
  return *reinterpret_cast<ushort*>(&h);
}
static __device__ __forceinline__ float bf2f(ushort u) {
  union { unsigned int u32; float f; } c;
  c.u32 = ((unsigned int)u) << 16;
  return c.f;
}
// cheap exact split: hi = truncated top-16 bits (exact subtraction), rem returned
static __device__ __forceinline__ ushort trunc_bf(float f, float* rem) {
  union { float f; unsigned int u; } a; a.f = f;
  union { float f; unsigned int u; } h; h.u = a.u & 0xFFFF0000u;
  *rem = f - h.f;                 // exact
  return (ushort)(a.u >> 16);
}
// cheap round-to-nearest (ties up) bf16 — 2 ops, no NaN path needed here
static __device__ __forceinline__ ushort rne_bf(float f) {
  union { float f; unsigned int u; } a; a.f = f;
  return (ushort)((a.u + 0x8000u) >> 16);
}

// K0: split Wq/Wk/Wv into bf16 hi/mid/lo triples [br][s][c]; Wl into hi/lo [c][s]
__global__ __launch_bounds__(256) void prep_kernel(const float* __restrict__ Wq,
                                                   const float* __restrict__ Wk,
                                                   const float* __restrict__ Wv,
                                                   const float* __restrict__ Wl,
                                                   ushort* __restrict__ whi,
                                                   ushort* __restrict__ wmid,
                                                   ushort* __restrict__ wlo,
                                                   ushort* __restrict__ wlhi,
                                                   ushort* __restrict__ wllo) {
  const int idx = blockIdx.x * 1024 + threadIdx.x * 4;
  if (blockIdx.y == 3) {  // Wl -> hi/lo
    float4 f = *reinterpret_cast<const float4*>(&Wl[idx]);
    ushort4 h, l;
    float r;
    h.x = trunc_bf(f.x, &r); l.x = rne_bf(r);
    h.y = trunc_bf(f.y, &r); l.y = rne_bf(r);
    h.z = trunc_bf(f.z, &r); l.z = rne_bf(r);
    h.w = trunc_bf(f.w, &r); l.w = rne_bf(r);
    *reinterpret_cast<ushort4*>(&wlhi[idx]) = h;
    *reinterpret_cast<ushort4*>(&wllo[idx]) = l;
    return;
  }
  const float* W = blockIdx.y == 0 ? Wq : (blockIdx.y == 1 ? Wk : Wv);
  float4 f = *reinterpret_cast<const float4*>(&W[idx]);
  ushort4 h, m, l;
  float r, r2;
  h.x = f2bf(f.x); r = f.x - bf2f(h.x); m.x = f2bf(r); r2 = r - bf2f(m.x); l.x = f2bf(r2);
  h.y = f2bf(f.y); r = f.y - bf2f(h.y); m.y = f2bf(r); r2 = r - bf2f(m.y); l.y = f2bf(r2);
  h.z = f2bf(f.z); r = f.z - bf2f(h.z); m.z = f2bf(r); r2 = r - bf2f(m.z); l.z = f2bf(r2);
  h.w = f2bf(f.w); r = f.w - bf2f(h.w); m.w = f2bf(r); r2 = r - bf2f(m.w); l.w = f2bf(r2);
  const size_t o = (size_t)blockIdx.y * (SDIM * CCH) + idx;
  *reinterpret_cast<ushort4*>(&whi[o])  = h;
  *reinterpret_cast<ushort4*>(&wmid[o]) = m;
  *reinterpret_cast<ushort4*>(&wlo[o])  = l;
}

// K1: 3-way-split bf16 MFMA projection, Ootomo two-accumulator, M=128.
//   r13 structure; x-split now via cheap trunc/trunc/rne (8 VALU/value vs ~35).
//   ap[br][hw][b][s] = sum_c x_br[b][c][hw] * w_br[s][c]
__global__ __launch_bounds__(256) void proj_mfma_kernel(const float* __restrict__ q,
                                                        const float* __restrict__ k,
                                                        const float* __restrict__ v,
                                                        const ushort* __restrict__ whi,
                                                        const ushort* __restrict__ wmid,
                                                        const ushort* __restrict__ wlo,
                                                        float* __restrict__ ap) {
  __shared__ float Xs[64 * 128];   // 32 KB, XOR-swizzled [c][hw]
  const int mt = blockIdx.x;   // hw tile of 128
  const int b = blockIdx.y;
  const int br = blockIdx.z;
  const float* x = br == 0 ? q : (br == 1 ? k : v);
  const ushort* wh = whi + (size_t)br * SDIM * CCH;
  const ushort* wm = wmid + (size_t)br * SDIM * CCH;
  const ushort* wl = wlo + (size_t)br * SDIM * CCH;
  float* apo = ap + (size_t)br * HW * 512;
  const int hw0 = mt * 128;
  const int tid = threadIdx.x;
  const int l = tid & 63;
  const int wstrip = (tid >> 6) * 32;  // wave's 32-row m-strip
  const int row16 = l & 15;
  const int kgrp = l >> 4;

  f32x4 acc_hi[2][4] = {};
  f32x4 acc_co[2][4] = {};

  for (int c0 = 0; c0 < CCH; c0 += 64) {
    __syncthreads();
    // stage [64 c][128 hw] f32 via float4 (16B/lane), XOR swizzle on hw
#pragma unroll
    for (int it = 0; it < 8; ++it) {
      const int fidx = (it * 256 + tid) * 4;
      const int cc = fidx >> 7;
      const int hwi = fidx & 127;
      const int hws = hwi ^ (((cc >> 3) & 1) << 4);
      *reinterpret_cast<float4*>(&Xs[cc * 128 + hws]) =
          *reinterpret_cast<const float4*>(&x[(size_t)(b * CCH + c0 + cc) * HW + hw0 + hwi]);
    }
    __syncthreads();
#pragma unroll
    for (int ks = 0; ks < 2; ++ks) {
      short8 bh[4], bm[4], bl[4];
#pragma unroll
      for (int nf = 0; nf < 4; ++nf) {
        const size_t off = (size_t)(nf * 16 + row16) * CCH + c0 + ks * 32 + kgrp * 8;
        bh[nf] = *reinterpret_cast<const short8*>(&wh[off]);
        bm[nf] = *reinterpret_cast<const short8*>(&wm[off]);
        bl[nf] = *reinterpret_cast<const short8*>(&wl[off]);
      }
#pragma unroll
      for (int mf = 0; mf < 2; ++mf) {
        const int rowA = wstrip + mf * 16 + row16;
        short8 ah, am, al;
        {
          ushort th[8], tm[8], tl[8];
#pragma unroll
          for (int i = 0; i < 8; ++i) {
            const int c = ks * 32 + kgrp * 8 + i;
            const float f = Xs[c * 128 + (rowA ^ (((c >> 3) & 1) << 4))];
            float r, r2;
            th[i] = trunc_bf(f, &r);     // exact
            tm[i] = trunc_bf(r, &r2);    // exact
            tl[i] = rne_bf(r2);          // only rounding: eps <= 2^-25 |x|
          }
          ah = *reinterpret_cast<const short8*>(th);
          am = *reinterpret_cast<const short8*>(tm);
          al = *reinterpret_cast<const short8*>(tl);
        }
#pragma unroll
        for (int nf = 0; nf < 4; ++nf) {
          // dominant term -> own accumulator
          acc_hi[mf][nf] = __builtin_amdgcn_mfma_f32_16x16x32_bf16(ah, bh[nf], acc_hi[mf][nf], 0, 0, 0);
          // correction terms -> separate accumulator
          acc_co[mf][nf] = __builtin_amdgcn_mfma_f32_16x16x32_bf16(ah, bm[nf], acc_co[mf][nf], 0, 0, 0);
          acc_co[mf][nf] = __builtin_amdgcn_mfma_f32_16x16x32_bf16(am, bh[nf], acc_co[mf][nf], 0, 0, 0);
          acc_co[mf][nf] = __builtin_amdgcn_mfma_f32_16x16x32_bf16(am, bm[nf], acc_co[mf][nf], 0, 0, 0);
          acc_co[mf][nf] = __builtin_amdgcn_mfma_f32_16x16x32_bf16(ah, bl[nf], acc_co[mf][nf], 0, 0, 0);
          acc_co[mf][nf] = __builtin_amdgcn_mfma_f32_16x16x32_bf16(al, bh[nf], acc_co[mf][nf], 0, 0, 0);
          acc_co[mf][nf] = __builtin_amdgcn_mfma_f32_16x16x32_bf16(am, bl[nf], acc_co[mf][nf], 0, 0, 0);
          acc_co[mf][nf] = __builtin_amdgcn_mfma_f32_16x16x32_bf16(al, bm[nf], acc_co[mf][nf], 0, 0, 0);
        }
      }
    }
  }
#pragma unroll
  for (int mf = 0; mf < 2; ++mf)
#pragma unroll
    for (int nf = 0; nf < 4; ++nf)
#pragma unroll
      for (int r = 0; r < 4; ++r) {
        const int m = hw0 + wstrip + mf * 16 + kgrp * 4 + r;
        apo[(size_t)m * 512 + b * 64 + nf * 16 + row16] = acc_hi[mf][nf][r] + acc_co[mf][nf][r];
      }
}

// K2: rD[br][h][s][t] = 1 / sum_w exp( sum_b A[h,w,b,s]*B[h,w,b,t] )
__global__ __launch_bounds__(512) void denom_kernel(const float* __restrict__ ap,
                                                    float* __restrict__ rD) {
  __shared__ float As[8 * 16];   // [b][s_local]
  __shared__ float Bs[8 * 64];   // [b][t]
  const int h = blockIdx.x, br = blockIdx.y, sq = blockIdx.z;
  const float* A  = ap + ((size_t)br * HW + (size_t)h * 64) * (BDIM * SDIM);
  const float* Bp = ap + ((size_t)((br + 1) % 3) * HW + (size_t)h * 64) * (BDIM * SDIM);
  const int tid = threadIdx.x;
  const int t = tid & 63;
  const int sg = tid >> 6;  // 0..7, each covers 2 s
  float D[2] = {};
  for (int w = 0; w < 64; ++w) {
    __syncthreads();
    if (tid < 128) As[tid] = A[w * 512 + (tid >> 4) * 64 + sq * 16 + (tid & 15)];
    Bs[tid] = Bp[w * 512 + tid];
    __syncthreads();
    float bv[8];
#pragma unroll
    for (int b = 0; b < 8; ++b) bv[b] = Bs[b * 64 + t];
#pragma unroll
    for (int j = 0; j < 2; ++j) {
      const int sl = sg * 2 + j;
      float m = 0.f;
#pragma unroll
      for (int b = 0; b < 8; ++b) m = fmaf(As[b * 16 + sl], bv[b], m);
      D[j] += __expf(m);
    }
  }
#pragma unroll
  for (int j = 0; j < 2; ++j)
    rD[((size_t)(br * 64 + h) * 64 + sq * 16 + sg * 2 + j) * 64 + t] = 1.0f / D[j];
}

// K3: on[br][hw][b][s] = o[s][b]/N[b], o = mtilde * C^T  (unchanged)
__global__ __launch_bounds__(256) void attn_kernel(const float* __restrict__ ap,
                                                   const float* __restrict__ rD,
                                                   float* __restrict__ on) {
  __shared__ float As[8 * 64], Bs[8 * 64], Cs[8 * 64];
  __shared__ float Ms[64 * 68];  // [s][t] padded
  const int wc = blockIdx.x, h = blockIdx.y, br = blockIdx.z;
  const float* A  = ap + ((size_t)br * HW + h * 64) * 512;
  const float* Bp = ap + ((size_t)((br + 1) % 3) * HW + h * 64) * 512;
  const float* Cp = ap + ((size_t)((br + 2) % 3) * HW + h * 64) * 512;
  const float* rDp = rD + (size_t)(br * 64 + h) * 4096;  // [s][t]
  const int tid = threadIdx.x;
  for (int w = wc * 8; w < wc * 8 + 8; ++w) {
    __syncthreads();
#pragma unroll
    for (int it = 0; it < 2; ++it) {
      int idx = it * 256 + tid;
      As[idx] = A[w * 512 + idx];
      Bs[idx] = Bp[w * 512 + idx];
      Cs[idx] = Cp[w * 512 + idx];
    }
    __syncthreads();
    {
      const int t = tid & 63, sg = tid >> 6;
      float bv[8];
#pragma unroll
      for (int b = 0; b < 8; ++b) bv[b] = Bs[b * 64 + t];
#pragma unroll
      for (int j = 0; j < 16; ++j) {
        int s = sg * 16 + j;
        float m = 0.f;
#pragma unroll
        for (int b = 0; b < 8; ++b) m = fmaf(As[b * 64 + s], bv[b], m);
        Ms[s * 68 + t] = __expf(m) * rDp[s * 64 + t];
      }
    }
    __syncthreads();
    const int s2 = tid & 63, bq = tid >> 6;
    float o0 = 0.f, o1 = 0.f;
#pragma unroll
    for (int tt = 0; tt < 64; tt += 4) {
      float4 mv = *reinterpret_cast<const float4*>(&Ms[s2 * 68 + tt]);
      float4 c0 = *reinterpret_cast<const float4*>(&Cs[bq * 64 + tt]);
      float4 c1 = *reinterpret_cast<const float4*>(&Cs[(bq + 4) * 64 + tt]);
      o0 = fmaf(mv.w, c0.w, fmaf(mv.z, c0.z, fmaf(mv.y, c0.y, fmaf(mv.x, c0.x, o0))));
      o1 = fmaf(mv.w, c1.w, fmaf(mv.z, c1.z, fmaf(mv.y, c1.y, fmaf(mv.x, c1.x, o1))));
    }
    float n0 = o0, n1 = o1;
#pragma unroll
    for (int off = 32; off > 0; off >>= 1) {
      n0 += __shfl_xor(n0, off);
      n1 += __shfl_xor(n1, off);
    }
    const float r0 = 1.0f / n0, r1 = 1.0f / n1;
    const size_t ob = ((size_t)br * HW + h * 64 + w) * 512;
    on[ob + (size_t)bq * 64 + s2] = o0 * r0;
    on[ob + (size_t)(bq + 4) * 64 + s2] = o1 * r1;
  }
}

// K4: out[brb][c][hw] = sum_s on[br][hw][b][s] * wl[c][s]
//   MFMA role-swap; Wl hi/lo pre-split (prep); on-split via cheap trunc+rne
__global__ __launch_bounds__(256) void out_kernel(const float* __restrict__ on,
                                                  const ushort* __restrict__ wlhi,
                                                  const ushort* __restrict__ wllo,
                                                  float* __restrict__ out) {
  __shared__ float Os[128 * 68];  // [hw_local][s] pad 68
  const int hwt = blockIdx.x;     // 32 tiles of 128 hw
  const int brb = blockIdx.y;     // 0..23
  const int br = brb >> 3, b = brb & 7;
  const int hw0 = hwt * 128;
  const int tid = threadIdx.x;
  const int l = tid & 63;
  const int wv = tid >> 6;        // wave 0..3 -> hw strip of 32
  const int l15 = l & 15;
  const int kgrp = l >> 4;

  {
    const int row = tid >> 4;
    const int s4 = (tid & 15) * 4;
#pragma unroll
    for (int it = 0; it < 8; ++it) {
      const int r = row + it * 16;
      *reinterpret_cast<float4*>(&Os[r * 68 + s4]) =
          *reinterpret_cast<const float4*>(&on[((size_t)(br * HW + hw0 + r) * 8 + b) * 64 + s4]);
    }
  }
  __syncthreads();

  short8 onh[2][2], onl[2][2];
#pragma unroll
  for (int nf = 0; nf < 2; ++nf)
#pragma unroll
    for (int ks = 0; ks < 2; ++ks) {
      const int row = wv * 32 + nf * 16 + l15;
      const float* p = &Os[row * 68 + ks * 32 + kgrp * 8];
      ushort th[8], tl[8];
#pragma unroll
      for (int i = 0; i < 8; ++i) {
        float r;
        th[i] = trunc_bf(p[i], &r);
        tl[i] = rne_bf(r);
      }
      onh[nf][ks] = *reinterpret_cast<const short8*>(th);
      onl[nf][ks] = *reinterpret_cast<const short8*>(tl);
    }

  for (int mf = 0; mf < 32; ++mf) {
    f32x4 acc[2] = {};
#pragma unroll
    for (int ks = 0; ks < 2; ++ks) {
      const size_t woff = (size_t)(mf * 16 + l15) * 64 + ks * 32 + kgrp * 8;
      const short8 wh8 = *reinterpret_cast<const short8*>(&wlhi[woff]);
      const short8 wl8 = *reinterpret_cast<const short8*>(&wllo[woff]);
#pragma unroll
      for (int nf = 0; nf < 2; ++nf) {
        acc[nf] = __builtin_amdgcn_mfma_f32_16x16x32_bf16(wh8, onh[nf][ks], acc[nf], 0, 0, 0);
        acc[nf] = __builtin_amdgcn_mfma_f32_16x16x32_bf16(wh8, onl[nf][ks], acc[nf], 0, 0, 0);
        acc[nf] = __builtin_amdgcn_mfma_f32_16x16x32_bf16(wl8, onh[nf][ks], acc[nf], 0, 0, 0);
      }
    }
#pragma unroll
    for (int nf = 0; nf < 2; ++nf)
#pragma unroll
      for (int r = 0; r < 4; ++r) {
        const int cc = mf * 16 + kgrp * 4 + r;
        out[(size_t)(brb * 512 + cc) * HW + hw0 + wv * 32 + nf * 16 + l15] = acc[nf][r];
      }
  }
}

extern "C" void kernel_launch(void* const* d_in, const int* in_sizes, int n_in,
                              void* d_out, int out_size, void* d_ws, size_t ws_size,
                              hipStream_t stream) {
  const float* q  = (const float*)d_in[0];
  const float* k  = (const float*)d_in[1];
  const float* v  = (const float*)d_in[2];
  const float* Wq = (const float*)d_in[3];
  const float* Wk = (const float*)d_in[4];
  const float* Wv = (const float*)d_in[5];
  const float* Wl = (const float*)d_in[6];
  float* out = (float*)d_out;

  float* ap = (float*)d_ws;                         // 3*HW*B*S floats = 25.2 MB
  float* rD = ap + (size_t)3 * HW * 512;            // 3*64*64*64 floats = 3.1 MB
  float* on = rD + (size_t)3 * 64 * 64 * 64;        // 3*HW*B*S floats = 25.2 MB
  ushort* whi  = (ushort*)rD;                       // 192 KB, consumed before denom overwrites rD
  ushort* wmid = whi + (size_t)3 * SDIM * CCH;
  ushort* wlo  = wmid + (size_t)3 * SDIM * CCH;
  ushort* wlhi = (ushort*)(on + (size_t)3 * HW * 512);  // 64 KB, after on
  ushort* wllo = wlhi + (size_t)SDIM * CCH;             // 64 KB

  prep_kernel<<<dim3(32, 4), 256, 0, stream>>>(Wq, Wk, Wv, Wl, whi, wmid, wlo, wlhi, wllo);
  proj_mfma_kernel<<<dim3(32, 8, 3), 256, 0, stream>>>(q, k, v, whi, wmid, wlo, ap);
  denom_kernel<<<dim3(64, 3, 4), 512, 0, stream>>>(ap, rD);
  attn_kernel<<<dim3(8, 64, 3), 256, 0, stream>>>(ap, rD, on);
  out_kernel<<<dim3(32, 24), 256, 0, stream>>>(on, wlhi, wllo, out);
}

// Round 15
// 280.644 us; speedup vs baseline: 1.1732x; 1.0084x over previous
//
#include <hip/hip_runtime.h>
#include <hip/hip_bf16.h>

#define HW 4096
#define CCH 512
#define SDIM 64
#define BDIM 8

typedef __attribute__((ext_vector_type(8))) short short8;
typedef __attribute__((ext_vector_type(4))) float f32x4;

static __device__ __forceinline__ ushort f2bf(float f) {
  __hip_bfloat16 h = __float2bfloat16(f);  // RNE (cold paths only)
  return *reinterpret_cast<ushort*>(&h);
}
static __device__ __forceinline__ float bf2f(ushort u) {
  union { unsigned int u32; float f; } c;
  c.u32 = ((unsigned int)u) << 16;
  return c.f;
}
// cheap exact split: hi = truncated top-16 bits (exact subtraction), rem returned
static __device__ __forceinline__ ushort trunc_bf(float f, float* rem) {
  union { float f; unsigned int u; } a; a.f = f;
  union { float f; unsigned int u; } h; h.u = a.u & 0xFFFF0000u;
  *rem = f - h.f;                 // exact
  return (ushort)(a.u >> 16);
}
static __device__ __forceinline__ ushort rne_bf(float f) {
  union { float f; unsigned int u; } a; a.f = f;
  return (ushort)((a.u + 0x8000u) >> 16);
}
// async global->LDS DMA: each lane contributes 16B; dest = uniform base + lane*16
static __device__ __forceinline__ void gll16(const float* g, float* lds_base) {
  __builtin_amdgcn_global_load_lds(
      (const __attribute__((address_space(1))) unsigned int*)g,
      (__attribute__((address_space(3))) unsigned int*)lds_base, 16, 0, 0);
}

// K0: split Wq/Wk/Wv into bf16 hi/mid/lo triples [br][s][c]; Wl into hi/lo [c][s]
__global__ __launch_bounds__(256) void prep_kernel(const float* __restrict__ Wq,
                                                   const float* __restrict__ Wk,
                                                   const float* __restrict__ Wv,
                                                   const float* __restrict__ Wl,
                                                   ushort* __restrict__ whi,
                                                   ushort* __restrict__ wmid,
                                                   ushort* __restrict__ wlo,
                                                   ushort* __restrict__ wlhi,
                                                   ushort* __restrict__ wllo) {
  const int idx = blockIdx.x * 1024 + threadIdx.x * 4;
  if (blockIdx.y == 3) {  // Wl -> hi/lo
    float4 f = *reinterpret_cast<const float4*>(&Wl[idx]);
    ushort4 h, l;
    float r;
    h.x = trunc_bf(f.x, &r); l.x = rne_bf(r);
    h.y = trunc_bf(f.y, &r); l.y = rne_bf(r);
    h.z = trunc_bf(f.z, &r); l.z = rne_bf(r);
    h.w = trunc_bf(f.w, &r); l.w = rne_bf(r);
    *reinterpret_cast<ushort4*>(&wlhi[idx]) = h;
    *reinterpret_cast<ushort4*>(&wllo[idx]) = l;
    return;
  }
  const float* W = blockIdx.y == 0 ? Wq : (blockIdx.y == 1 ? Wk : Wv);
  float4 f = *reinterpret_cast<const float4*>(&W[idx]);
  ushort4 h, m, l;
  float r, r2;
  h.x = f2bf(f.x); r = f.x - bf2f(h.x); m.x = f2bf(r); r2 = r - bf2f(m.x); l.x = f2bf(r2);
  h.y = f2bf(f.y); r = f.y - bf2f(h.y); m.y = f2bf(r); r2 = r - bf2f(m.y); l.y = f2bf(r2);
  h.z = f2bf(f.z); r = f.z - bf2f(h.z); m.z = f2bf(r); r2 = r - bf2f(m.z); l.z = f2bf(r2);
  h.w = f2bf(f.w); r = f.w - bf2f(h.w); m.w = f2bf(r); r2 = r - bf2f(m.w); l.w = f2bf(r2);
  const size_t o = (size_t)blockIdx.y * (SDIM * CCH) + idx;
  *reinterpret_cast<ushort4*>(&whi[o])  = h;
  *reinterpret_cast<ushort4*>(&wmid[o]) = m;
  *reinterpret_cast<ushort4*>(&wlo[o])  = l;
}

// K1: 3-way-split bf16 MFMA projection, Ootomo two-accumulator, M=128.
//   Pipelined: per chunk(32c): [12 weight loads (L2)] -> [4 gll16 DMAs for
//   chunk+1] -> vmcnt(4) (this chunk's DMAs + weights done, next in flight) ->
//   raw s_barrier -> compute -> raw s_barrier. vmcnt in-order retirement
//   requires weights issued BEFORE the DMAs (else weight-use drains the queue).
//   ap[br][hw][b][s] = sum_c x_br[b][c][hw] * w_br[s][c]
__global__ __launch_bounds__(256) void proj_mfma_kernel(const float* __restrict__ q,
                                                        const float* __restrict__ k,
                                                        const float* __restrict__ v,
                                                        const ushort* __restrict__ whi,
                                                        const ushort* __restrict__ wmid,
                                                        const ushort* __restrict__ wlo,
                                                        float* __restrict__ ap) {
  __shared__ float Xs[2 * 32 * 128];   // 32 KB double buffer [buf][c_local][hw]
  const int mt = blockIdx.x;   // hw tile of 128
  const int b = blockIdx.y;
  const int br = blockIdx.z;
  const float* x = br == 0 ? q : (br == 1 ? k : v);
  const ushort* wh = whi + (size_t)br * SDIM * CCH;
  const ushort* wm = wmid + (size_t)br * SDIM * CCH;
  const ushort* wl = wlo + (size_t)br * SDIM * CCH;
  float* apo = ap + (size_t)br * HW * 512;
  const int hw0 = mt * 128;
  const int tid = threadIdx.x;
  const int l = tid & 63;
  const int wid = tid >> 6;
  const int wstrip = wid * 32;         // wave's 32-row m-strip
  const int row16 = l & 15;
  const int kgrp = l >> 4;
  const float* xcol = x + (size_t)b * CCH * HW + hw0;
  const int rbase = 8 * wid;           // wave stages rows [8w, 8w+8)
  const int rsub = l >> 5;             // lanes 0-31 -> row +0, 32-63 -> row +1
  const int hws = (l & 31) * 4;        // lane's 16B slot within a 512B row

  f32x4 acc_hi[2][4] = {};
  f32x4 acc_co[2][4] = {};

  // prologue: stage chunk 0 into buf 0
#pragma unroll
  for (int j = 0; j < 4; ++j) {
    const int r = rbase + 2 * j + rsub;
    gll16(xcol + (size_t)r * HW + hws, &Xs[(rbase + 2 * j) * 128]);
  }

  for (int ci = 0; ci < 16; ++ci) {
    // 1) weight fragments for THIS chunk (oldest in vmcnt queue)
    short8 bh[4], bm[4], bl[4];
#pragma unroll
    for (int nf = 0; nf < 4; ++nf) {
      const size_t off = (size_t)(nf * 16 + row16) * CCH + ci * 32 + kgrp * 8;
      bh[nf] = *reinterpret_cast<const short8*>(&wh[off]);
      bm[nf] = *reinterpret_cast<const short8*>(&wm[off]);
      bl[nf] = *reinterpret_cast<const short8*>(&wl[off]);
    }
    __builtin_amdgcn_sched_barrier(0);
    // 2) DMA-stage NEXT chunk (stays in flight across barrier + compute)
    if (ci < 15) {
      float* dst = &Xs[((ci + 1) & 1) * 4096];
#pragma unroll
      for (int j = 0; j < 4; ++j) {
        const int r = rbase + 2 * j + rsub;
        gll16(xcol + (size_t)((ci + 1) * 32 + r) * HW + hws, dst + (rbase + 2 * j) * 128);
      }
      __builtin_amdgcn_sched_barrier(0);
      asm volatile("s_waitcnt vmcnt(4)" ::: "memory");  // weights + my chunk-ci DMAs done
    } else {
      asm volatile("s_waitcnt vmcnt(0)" ::: "memory");
    }
    __builtin_amdgcn_sched_barrier(0);
    __builtin_amdgcn_s_barrier();      // all waves' chunk-ci rows landed
    __builtin_amdgcn_sched_barrier(0);

    // 3) compute chunk ci
    const float* lw = &Xs[(ci & 1) * 4096];
#pragma unroll
    for (int mf = 0; mf < 2; ++mf) {
      const int rowA = wstrip + mf * 16 + row16;
      short8 ah, am, al;
      {
        ushort th[8], tm[8], tl[8];
#pragma unroll
        for (int i = 0; i < 8; ++i) {
          const float f = lw[(kgrp * 8 + i) * 128 + rowA];
          float r, r2;
          th[i] = trunc_bf(f, &r);     // exact
          tm[i] = trunc_bf(r, &r2);    // exact
          tl[i] = rne_bf(r2);          // only rounding: eps <= 2^-25 |x|
        }
        ah = *reinterpret_cast<const short8*>(th);
        am = *reinterpret_cast<const short8*>(tm);
        al = *reinterpret_cast<const short8*>(tl);
      }
#pragma unroll
      for (int nf = 0; nf < 4; ++nf) {
        acc_hi[mf][nf] = __builtin_amdgcn_mfma_f32_16x16x32_bf16(ah, bh[nf], acc_hi[mf][nf], 0, 0, 0);
        acc_co[mf][nf] = __builtin_amdgcn_mfma_f32_16x16x32_bf16(ah, bm[nf], acc_co[mf][nf], 0, 0, 0);
        acc_co[mf][nf] = __builtin_amdgcn_mfma_f32_16x16x32_bf16(am, bh[nf], acc_co[mf][nf], 0, 0, 0);
        acc_co[mf][nf] = __builtin_amdgcn_mfma_f32_16x16x32_bf16(am, bm[nf], acc_co[mf][nf], 0, 0, 0);
        acc_co[mf][nf] = __builtin_amdgcn_mfma_f32_16x16x32_bf16(ah, bl[nf], acc_co[mf][nf], 0, 0, 0);
        acc_co[mf][nf] = __builtin_amdgcn_mfma_f32_16x16x32_bf16(al, bh[nf], acc_co[mf][nf], 0, 0, 0);
        acc_co[mf][nf] = __builtin_amdgcn_mfma_f32_16x16x32_bf16(am, bl[nf], acc_co[mf][nf], 0, 0, 0);
        acc_co[mf][nf] = __builtin_amdgcn_mfma_f32_16x16x32_bf16(al, bm[nf], acc_co[mf][nf], 0, 0, 0);
      }
    }
    __builtin_amdgcn_sched_barrier(0);
    __builtin_amdgcn_s_barrier();      // all waves done reading buf[ci&1] before it's re-staged
    __builtin_amdgcn_sched_barrier(0);
  }

#pragma unroll
  for (int mf = 0; mf < 2; ++mf)
#pragma unroll
    for (int nf = 0; nf < 4; ++nf)
#pragma unroll
      for (int r = 0; r < 4; ++r) {
        const int m = hw0 + wstrip + mf * 16 + kgrp * 4 + r;
        apo[(size_t)m * 512 + b * 64 + nf * 16 + row16] = acc_hi[mf][nf][r] + acc_co[mf][nf][r];
      }
}

// K2: rD[br][h][s][t] = 1 / sum_w exp( sum_b A[h,w,b,s]*B[h,w,b,t] )
__global__ __launch_bounds__(512) void denom_kernel(const float* __restrict__ ap,
                                                    float* __restrict__ rD) {
  __shared__ float As[8 * 16];   // [b][s_local]
  __shared__ float Bs[8 * 64];   // [b][t]
  const int h = blockIdx.x, br = blockIdx.y, sq = blockIdx.z;
  const float* A  = ap + ((size_t)br * HW + (size_t)h * 64) * (BDIM * SDIM);
  const float* Bp = ap + ((size_t)((br + 1) % 3) * HW + (size_t)h * 64) * (BDIM * SDIM);
  const int tid = threadIdx.x;
  const int t = tid & 63;
  const int sg = tid >> 6;  // 0..7, each covers 2 s
  float D[2] = {};
  for (int w = 0; w < 64; ++w) {
    __syncthreads();
    if (tid < 128) As[tid] = A[w * 512 + (tid >> 4) * 64 + sq * 16 + (tid & 15)];
    Bs[tid] = Bp[w * 512 + tid];
    __syncthreads();
    float bv[8];
#pragma unroll
    for (int b = 0; b < 8; ++b) bv[b] = Bs[b * 64 + t];
#pragma unroll
    for (int j = 0; j < 2; ++j) {
      const int sl = sg * 2 + j;
      float m = 0.f;
#pragma unroll
      for (int b = 0; b < 8; ++b) m = fmaf(As[b * 16 + sl], bv[b], m);
      D[j] += __expf(m);
    }
  }
#pragma unroll
  for (int j = 0; j < 2; ++j)
    rD[((size_t)(br * 64 + h) * 64 + sq * 16 + sg * 2 + j) * 64 + t] = 1.0f / D[j];
}

// K3: on[br][hw][b][s] = o[s][b]/N[b], o = mtilde * C^T
//   Ms stored TRANSPOSED [t][s] pad 65: m-write free, PV reads conflict-free
//   (was 8-way bank conflict on every b128 PV read with [s][68] layout).
__global__ __launch_bounds__(256) void attn_kernel(const float* __restrict__ ap,
                                                   const float* __restrict__ rD,
                                                   float* __restrict__ on) {
  __shared__ float As[8 * 64], Bs[8 * 64], Cs[8 * 64];
  __shared__ float Ms[64 * 65];  // [t][s] padded 65
  const int wc = blockIdx.x, h = blockIdx.y, br = blockIdx.z;
  const float* A  = ap + ((size_t)br * HW + h * 64) * 512;
  const float* Bp = ap + ((size_t)((br + 1) % 3) * HW + h * 64) * 512;
  const float* Cp = ap + ((size_t)((br + 2) % 3) * HW + h * 64) * 512;
  const float* rDp = rD + (size_t)(br * 64 + h) * 4096;  // [s][t]
  const int tid = threadIdx.x;
  for (int w = wc * 8; w < wc * 8 + 8; ++w) {
    __syncthreads();
#pragma unroll
    for (int it = 0; it < 2; ++it) {
      int idx = it * 256 + tid;
      As[idx] = A[w * 512 + idx];
      Bs[idx] = Bp[w * 512 + idx];
      Cs[idx] = Cp[w * 512 + idx];
    }
    __syncthreads();
    {
      const int t = tid & 63, sg = tid >> 6;
      float bv[8];
#pragma unroll
      for (int b = 0; b < 8; ++b) bv[b] = Bs[b * 64 + t];
#pragma unroll
      for (int j = 0; j < 16; ++j) {
        int s = sg * 16 + j;
        float m = 0.f;
#pragma unroll
        for (int b = 0; b < 8; ++b) m = fmaf(As[b * 64 + s], bv[b], m);
        Ms[t * 65 + s] = __expf(m) * rDp[s * 64 + t];   // transposed store
      }
    }
    __syncthreads();
    const int s2 = tid & 63, bq = tid >> 6;
    float o0 = 0.f, o1 = 0.f;
#pragma unroll
    for (int tt = 0; tt < 64; tt += 4) {
      const float m0 = Ms[(tt + 0) * 65 + s2];
      const float m1 = Ms[(tt + 1) * 65 + s2];
      const float m2 = Ms[(tt + 2) * 65 + s2];
      const float m3 = Ms[(tt + 3) * 65 + s2];
      float4 c0 = *reinterpret_cast<const float4*>(&Cs[bq * 64 + tt]);
      float4 c1 = *reinterpret_cast<const float4*>(&Cs[(bq + 4) * 64 + tt]);
      o0 = fmaf(m3, c0.w, fmaf(m2, c0.z, fmaf(m1, c0.y, fmaf(m0, c0.x, o0))));
      o1 = fmaf(m3, c1.w, fmaf(m2, c1.z, fmaf(m1, c1.y, fmaf(m0, c1.x, o1))));
    }
    float n0 = o0, n1 = o1;
#pragma unroll
    for (int off = 32; off > 0; off >>= 1) {
      n0 += __shfl_xor(n0, off);
      n1 += __shfl_xor(n1, off);
    }
    const float r0 = 1.0f / n0, r1 = 1.0f / n1;
    const size_t ob = ((size_t)br * HW + h * 64 + w) * 512;
    on[ob + (size_t)bq * 64 + s2] = o0 * r0;
    on[ob + (size_t)(bq + 4) * 64 + s2] = o1 * r1;
  }
}

// K4: out[brb][c][hw] = sum_s on[br][hw][b][s] * wl[c][s]  (MFMA role-swap)
__global__ __launch_bounds__(256) void out_kernel(const float* __restrict__ on,
                                                  const ushort* __restrict__ wlhi,
                                                  const ushort* __restrict__ wllo,
                                                  float* __restrict__ out) {
  __shared__ float Os[128 * 68];  // [hw_local][s] pad 68
  const int hwt = blockIdx.x;     // 32 tiles of 128 hw
  const int brb = blockIdx.y;     // 0..23
  const int br = brb >> 3, b = brb & 7;
  const int hw0 = hwt * 128;
  const int tid = threadIdx.x;
  const int l = tid & 63;
  const int wv = tid >> 6;        // wave 0..3 -> hw strip of 32
  const int l15 = l & 15;
  const int kgrp = l >> 4;

  {
    const int row = tid >> 4;
    const int s4 = (tid & 15) * 4;
#pragma unroll
    for (int it = 0; it < 8; ++it) {
      const int r = row + it * 16;
      *reinterpret_cast<float4*>(&Os[r * 68 + s4]) =
          *reinterpret_cast<const float4*>(&on[((size_t)(br * HW + hw0 + r) * 8 + b) * 64 + s4]);
    }
  }
  __syncthreads();

  short8 onh[2][2], onl[2][2];
#pragma unroll
  for (int nf = 0; nf < 2; ++nf)
#pragma unroll
    for (int ks = 0; ks < 2; ++ks) {
      const int row = wv * 32 + nf * 16 + l15;
      const float* p = &Os[row * 68 + ks * 32 + kgrp * 8];
      ushort th[8], tl[8];
#pragma unroll
      for (int i = 0; i < 8; ++i) {
        float r;
        th[i] = trunc_bf(p[i], &r);
        tl[i] = rne_bf(r);
      }
      onh[nf][ks] = *reinterpret_cast<const short8*>(th);
      onl[nf][ks] = *reinterpret_cast<const short8*>(tl);
    }

  for (int mf = 0; mf < 32; ++mf) {
    f32x4 acc[2] = {};
#pragma unroll
    for (int ks = 0; ks < 2; ++ks) {
      const size_t woff = (size_t)(mf * 16 + l15) * 64 + ks * 32 + kgrp * 8;
      const short8 wh8 = *reinterpret_cast<const short8*>(&wlhi[woff]);
      const short8 wl8 = *reinterpret_cast<const short8*>(&wllo[woff]);
#pragma unroll
      for (int nf = 0; nf < 2; ++nf) {
        acc[nf] = __builtin_amdgcn_mfma_f32_16x16x32_bf16(wh8, onh[nf][ks], acc[nf], 0, 0, 0);
        acc[nf] = __builtin_amdgcn_mfma_f32_16x16x32_bf16(wh8, onl[nf][ks], acc[nf], 0, 0, 0);
        acc[nf] = __builtin_amdgcn_mfma_f32_16x16x32_bf16(wl8, onh[nf][ks], acc[nf], 0, 0, 0);
      }
    }
#pragma unroll
    for (int nf = 0; nf < 2; ++nf)
#pragma unroll
      for (int r = 0; r < 4; ++r) {
        const int cc = mf * 16 + kgrp * 4 + r;
        out[(size_t)(brb * 512 + cc) * HW + hw0 + wv * 32 + nf * 16 + l15] = acc[nf][r];
      }
  }
}

extern "C" void kernel_launch(void* const* d_in, const int* in_sizes, int n_in,
                              void* d_out, int out_size, void* d_ws, size_t ws_size,
                              hipStream_t stream) {
  const float* q  = (const float*)d_in[0];
  const float* k  = (const float*)d_in[1];
  const float* v  = (const float*)d_in[2];
  const float* Wq = (const float*)d_in[3];
  const float* Wk = (const float*)d_in[4];
  const float* Wv = (const float*)d_in[5];
  const float* Wl = (const float*)d_in[6];
  float* out = (float*)d_out;

  float* ap = (float*)d_ws;                         // 3*HW*B*S floats = 25.2 MB
  float* rD = ap + (size_t)3 * HW * 512;            // 3*64*64*64 floats = 3.1 MB
  float* on = rD + (size_t)3 * 64 * 64 * 64;        // 3*HW*B*S floats = 25.2 MB
  ushort* whi  = (ushort*)rD;                       // 192 KB, consumed before denom overwrites rD
  ushort* wmid = whi + (size_t)3 * SDIM * CCH;
  ushort* wlo  = wmid + (size_t)3 * SDIM * CCH;
  ushort* wlhi = (ushort*)(on + (size_t)3 * HW * 512);  // 64 KB, after on
  ushort* wllo = wlhi + (size_t)SDIM * CCH;             // 64 KB

  prep_kernel<<<dim3(32, 4), 256, 0, stream>>>(Wq, Wk, Wv, Wl, whi, wmid, wlo, wlhi, wllo);
  proj_mfma_kernel<<<dim3(32, 8, 3), 256, 0, stream>>>(q, k, v, whi, wmid, wlo, ap);
  denom_kernel<<<dim3(64, 3, 4), 512, 0, stream>>>(ap, rD);
  attn_kernel<<<dim3(8, 64, 3), 256, 0, stream>>>(ap, rD, on);
  out_kernel<<<dim3(32, 24), 256, 0, stream>>>(on, wlhi, wllo, out);
}

// Round 16
// 276.340 us; speedup vs baseline: 1.1915x; 1.0156x over previous
//
#include <hip/hip_runtime.h>
#include <hip/hip_bf16.h>

#define HW 4096
#define CCH 512
#define SDIM 64
#define BDIM 8

typedef __attribute__((ext_vector_type(8))) short short8;
typedef __attribute__((ext_vector_type(4))) float f32x4;

static __device__ __forceinline__ ushort f2bf(float f) {
  __hip_bfloat16 h = __float2bfloat16(f);  // RNE (cold paths only)
  return *reinterpret_cast<ushort*>(&h);
}
static __device__ __forceinline__ float bf2f(ushort u) {
  union { unsigned int u32; float f; } c;
  c.u32 = ((unsigned int)u) << 16;
  return c.f;
}
// cheap exact split: hi = truncated top-16 bits (exact subtraction), rem returned
static __device__ __forceinline__ ushort trunc_bf(float f, float* rem) {
  union { float f; unsigned int u; } a; a.f = f;
  union { float f; unsigned int u; } h; h.u = a.u & 0xFFFF0000u;
  *rem = f - h.f;                 // exact
  return (ushort)(a.u >> 16);
}
static __device__ __forceinline__ ushort rne_bf(float f) {
  union { float f; unsigned int u; } a; a.f = f;
  return (ushort)((a.u + 0x8000u) >> 16);
}
// async global->LDS DMA: each lane contributes 16B; dest = uniform base + lane*16
static __device__ __forceinline__ void gll16(const float* g, float* lds_base) {
  __builtin_amdgcn_global_load_lds(
      (const __attribute__((address_space(1))) unsigned int*)g,
      (__attribute__((address_space(3))) unsigned int*)lds_base, 16, 0, 0);
}

// K0: split Wq/Wk/Wv into bf16 hi/mid/lo triples [br][s][c]; Wl into hi/lo [c][s]
__global__ __launch_bounds__(256) void prep_kernel(const float* __restrict__ Wq,
                                                   const float* __restrict__ Wk,
                                                   const float* __restrict__ Wv,
                                                   const float* __restrict__ Wl,
                                                   ushort* __restrict__ whi,
                                                   ushort* __restrict__ wmid,
                                                   ushort* __restrict__ wlo,
                                                   ushort* __restrict__ wlhi,
                                                   ushort* __restrict__ wllo) {
  const int idx = blockIdx.x * 1024 + threadIdx.x * 4;
  if (blockIdx.y == 3) {  // Wl -> hi/lo
    float4 f = *reinterpret_cast<const float4*>(&Wl[idx]);
    ushort4 h, l;
    float r;
    h.x = trunc_bf(f.x, &r); l.x = rne_bf(r);
    h.y = trunc_bf(f.y, &r); l.y = rne_bf(r);
    h.z = trunc_bf(f.z, &r); l.z = rne_bf(r);
    h.w = trunc_bf(f.w, &r); l.w = rne_bf(r);
    *reinterpret_cast<ushort4*>(&wlhi[idx]) = h;
    *reinterpret_cast<ushort4*>(&wllo[idx]) = l;
    return;
  }
  const float* W = blockIdx.y == 0 ? Wq : (blockIdx.y == 1 ? Wk : Wv);
  float4 f = *reinterpret_cast<const float4*>(&W[idx]);
  ushort4 h, m, l;
  float r, r2;
  h.x = f2bf(f.x); r = f.x - bf2f(h.x); m.x = f2bf(r); r2 = r - bf2f(m.x); l.x = f2bf(r2);
  h.y = f2bf(f.y); r = f.y - bf2f(h.y); m.y = f2bf(r); r2 = r - bf2f(m.y); l.y = f2bf(r2);
  h.z = f2bf(f.z); r = f.z - bf2f(h.z); m.z = f2bf(r); r2 = r - bf2f(m.z); l.z = f2bf(r2);
  h.w = f2bf(f.w); r = f.w - bf2f(h.w); m.w = f2bf(r); r2 = r - bf2f(m.w); l.w = f2bf(r2);
  const size_t o = (size_t)blockIdx.y * (SDIM * CCH) + idx;
  *reinterpret_cast<ushort4*>(&whi[o])  = h;
  *reinterpret_cast<ushort4*>(&wmid[o]) = m;
  *reinterpret_cast<ushort4*>(&wlo[o])  = l;
}

// K1: 3-way-split bf16 MFMA projection, Ootomo two-accumulator, M=128.
//   TRIPLE-buffered, TWO-chunk-ahead DMA pipeline: per chunk(32c):
//   [12 weight loads] -> [4 gll16 DMAs for chunk+2] -> vmcnt(8) (this chunk's
//   DMAs + weights done; chunks +1,+2 stay in flight) -> raw s_barrier ->
//   compute -> end s_barrier (orders buffer reuse). In-order vmcnt retirement
//   requires weights issued BEFORE the DMAs.
//   ap[br][hw][b][s] = sum_c x_br[b][c][hw] * w_br[s][c]
__global__ __launch_bounds__(256) void proj_mfma_kernel(const float* __restrict__ q,
                                                        const float* __restrict__ k,
                                                        const float* __restrict__ v,
                                                        const ushort* __restrict__ whi,
                                                        const ushort* __restrict__ wmid,
                                                        const ushort* __restrict__ wlo,
                                                        float* __restrict__ ap) {
  __shared__ float Xs[3 * 32 * 128];   // 48 KB triple buffer [buf][c_local][hw]
  const int mt = blockIdx.x;   // hw tile of 128
  const int b = blockIdx.y;
  const int br = blockIdx.z;
  const float* x = br == 0 ? q : (br == 1 ? k : v);
  const ushort* wh = whi + (size_t)br * SDIM * CCH;
  const ushort* wm = wmid + (size_t)br * SDIM * CCH;
  const ushort* wl = wlo + (size_t)br * SDIM * CCH;
  float* apo = ap + (size_t)br * HW * 512;
  const int hw0 = mt * 128;
  const int tid = threadIdx.x;
  const int l = tid & 63;
  const int wid = tid >> 6;
  const int wstrip = wid * 32;         // wave's 32-row m-strip
  const int row16 = l & 15;
  const int kgrp = l >> 4;
  const float* xcol = x + (size_t)b * CCH * HW + hw0;
  const int rbase = 8 * wid;           // wave stages rows [8w, 8w+8)
  const int rsub = l >> 5;             // lanes 0-31 -> row +0, 32-63 -> row +1
  const int hws = (l & 31) * 4;        // lane's 16B slot within a 512B row

  f32x4 acc_hi[2][4] = {};
  f32x4 acc_co[2][4] = {};

  // prologue: stage chunks 0,1 into bufs 0,1
#pragma unroll
  for (int j = 0; j < 4; ++j) {
    const int r = rbase + 2 * j + rsub;
    gll16(xcol + (size_t)r * HW + hws, &Xs[(rbase + 2 * j) * 128]);
  }
#pragma unroll
  for (int j = 0; j < 4; ++j) {
    const int r = rbase + 2 * j + rsub;
    gll16(xcol + (size_t)(32 + r) * HW + hws, &Xs[4096 + (rbase + 2 * j) * 128]);
  }

  for (int ci = 0; ci < 16; ++ci) {
    // 1) weight fragments for THIS chunk (older than the new DMAs in the queue)
    short8 bh[4], bm[4], bl[4];
#pragma unroll
    for (int nf = 0; nf < 4; ++nf) {
      const size_t off = (size_t)(nf * 16 + row16) * CCH + ci * 32 + kgrp * 8;
      bh[nf] = *reinterpret_cast<const short8*>(&wh[off]);
      bm[nf] = *reinterpret_cast<const short8*>(&wm[off]);
      bl[nf] = *reinterpret_cast<const short8*>(&wl[off]);
    }
    __builtin_amdgcn_sched_barrier(0);
    // 2) DMA-stage chunk ci+2 (buffer reuse safe: last reader finished at the
    //    end-barrier of iteration ci-1)
    if (ci < 14) {
      float* dst = &Xs[((ci + 2) % 3) * 4096];
#pragma unroll
      for (int j = 0; j < 4; ++j) {
        const int r = rbase + 2 * j + rsub;
        gll16(xcol + (size_t)((ci + 2) * 32 + r) * HW + hws, dst + (rbase + 2 * j) * 128);
      }
      __builtin_amdgcn_sched_barrier(0);
      asm volatile("s_waitcnt vmcnt(8)" ::: "memory");  // weights + chunk-ci DMAs done
    } else if (ci == 14) {
      asm volatile("s_waitcnt vmcnt(4)" ::: "memory");  // leave chunk-15 DMAs in flight
    } else {
      asm volatile("s_waitcnt vmcnt(0)" ::: "memory");
    }
    __builtin_amdgcn_sched_barrier(0);
    __builtin_amdgcn_s_barrier();      // all waves' chunk-ci rows landed
    __builtin_amdgcn_sched_barrier(0);

    // 3) compute chunk ci
    const float* lw = &Xs[(ci % 3) * 4096];
#pragma unroll
    for (int mf = 0; mf < 2; ++mf) {
      const int rowA = wstrip + mf * 16 + row16;
      short8 ah, am, al;
      {
        ushort th[8], tm[8], tl[8];
#pragma unroll
        for (int i = 0; i < 8; ++i) {
          const float f = lw[(kgrp * 8 + i) * 128 + rowA];
          float r, r2;
          th[i] = trunc_bf(f, &r);     // exact
          tm[i] = trunc_bf(r, &r2);    // exact
          tl[i] = rne_bf(r2);          // only rounding: eps <= 2^-25 |x|
        }
        ah = *reinterpret_cast<const short8*>(th);
        am = *reinterpret_cast<const short8*>(tm);
        al = *reinterpret_cast<const short8*>(tl);
      }
#pragma unroll
      for (int nf = 0; nf < 4; ++nf) {
        acc_hi[mf][nf] = __builtin_amdgcn_mfma_f32_16x16x32_bf16(ah, bh[nf], acc_hi[mf][nf], 0, 0, 0);
        acc_co[mf][nf] = __builtin_amdgcn_mfma_f32_16x16x32_bf16(ah, bm[nf], acc_co[mf][nf], 0, 0, 0);
        acc_co[mf][nf] = __builtin_amdgcn_mfma_f32_16x16x32_bf16(am, bh[nf], acc_co[mf][nf], 0, 0, 0);
        acc_co[mf][nf] = __builtin_amdgcn_mfma_f32_16x16x32_bf16(am, bm[nf], acc_co[mf][nf], 0, 0, 0);
        acc_co[mf][nf] = __builtin_amdgcn_mfma_f32_16x16x32_bf16(ah, bl[nf], acc_co[mf][nf], 0, 0, 0);
        acc_co[mf][nf] = __builtin_amdgcn_mfma_f32_16x16x32_bf16(al, bh[nf], acc_co[mf][nf], 0, 0, 0);
        acc_co[mf][nf] = __builtin_amdgcn_mfma_f32_16x16x32_bf16(am, bl[nf], acc_co[mf][nf], 0, 0, 0);
        acc_co[mf][nf] = __builtin_amdgcn_mfma_f32_16x16x32_bf16(al, bm[nf], acc_co[mf][nf], 0, 0, 0);
      }
    }
    __builtin_amdgcn_sched_barrier(0);
    __builtin_amdgcn_s_barrier();      // all waves done reading buf[ci%3]
    __builtin_amdgcn_sched_barrier(0);
  }

#pragma unroll
  for (int mf = 0; mf < 2; ++mf)
#pragma unroll
    for (int nf = 0; nf < 4; ++nf)
#pragma unroll
      for (int r = 0; r < 4; ++r) {
        const int m = hw0 + wstrip + mf * 16 + kgrp * 4 + r;
        apo[(size_t)m * 512 + b * 64 + nf * 16 + row16] = acc_hi[mf][nf][r] + acc_co[mf][nf][r];
      }
}

// K2: rD[br][h][s][t] = 1 / sum_w exp( sum_b A[h,w,b,s]*B[h,w,b,t] )
__global__ __launch_bounds__(512) void denom_kernel(const float* __restrict__ ap,
                                                    float* __restrict__ rD) {
  __shared__ float As[8 * 16];   // [b][s_local]
  __shared__ float Bs[8 * 64];   // [b][t]
  const int h = blockIdx.x, br = blockIdx.y, sq = blockIdx.z;
  const float* A  = ap + ((size_t)br * HW + (size_t)h * 64) * (BDIM * SDIM);
  const float* Bp = ap + ((size_t)((br + 1) % 3) * HW + (size_t)h * 64) * (BDIM * SDIM);
  const int tid = threadIdx.x;
  const int t = tid & 63;
  const int sg = tid >> 6;  // 0..7, each covers 2 s
  float D[2] = {};
  for (int w = 0; w < 64; ++w) {
    __syncthreads();
    if (tid < 128) As[tid] = A[w * 512 + (tid >> 4) * 64 + sq * 16 + (tid & 15)];
    Bs[tid] = Bp[w * 512 + tid];
    __syncthreads();
    float bv[8];
#pragma unroll
    for (int b = 0; b < 8; ++b) bv[b] = Bs[b * 64 + t];
#pragma unroll
    for (int j = 0; j < 2; ++j) {
      const int sl = sg * 2 + j;
      float m = 0.f;
#pragma unroll
      for (int b = 0; b < 8; ++b) m = fmaf(As[b * 16 + sl], bv[b], m);
      D[j] += __expf(m);
    }
  }
#pragma unroll
  for (int j = 0; j < 2; ++j)
    rD[((size_t)(br * 64 + h) * 64 + sq * 16 + sg * 2 + j) * 64 + t] = 1.0f / D[j];
}

// K3: on[br][hw][b][s] = o[s][b]/N[b], o = mtilde * C^T  (Ms transposed [t][s])
__global__ __launch_bounds__(256) void attn_kernel(const float* __restrict__ ap,
                                                   const float* __restrict__ rD,
                                                   float* __restrict__ on) {
  __shared__ float As[8 * 64], Bs[8 * 64], Cs[8 * 64];
  __shared__ float Ms[64 * 65];  // [t][s] padded 65
  const int wc = blockIdx.x, h = blockIdx.y, br = blockIdx.z;
  const float* A  = ap + ((size_t)br * HW + h * 64) * 512;
  const float* Bp = ap + ((size_t)((br + 1) % 3) * HW + h * 64) * 512;
  const float* Cp = ap + ((size_t)((br + 2) % 3) * HW + h * 64) * 512;
  const float* rDp = rD + (size_t)(br * 64 + h) * 4096;  // [s][t]
  const int tid = threadIdx.x;
  for (int w = wc * 8; w < wc * 8 + 8; ++w) {
    __syncthreads();
#pragma unroll
    for (int it = 0; it < 2; ++it) {
      int idx = it * 256 + tid;
      As[idx] = A[w * 512 + idx];
      Bs[idx] = Bp[w * 512 + idx];
      Cs[idx] = Cp[w * 512 + idx];
    }
    __syncthreads();
    {
      const int t = tid & 63, sg = tid >> 6;
      float bv[8];
#pragma unroll
      for (int b = 0; b < 8; ++b) bv[b] = Bs[b * 64 + t];
#pragma unroll
      for (int j = 0; j < 16; ++j) {
        int s = sg * 16 + j;
        float m = 0.f;
#pragma unroll
        for (int b = 0; b < 8; ++b) m = fmaf(As[b * 64 + s], bv[b], m);
        Ms[t * 65 + s] = __expf(m) * rDp[s * 64 + t];   // transposed store
      }
    }
    __syncthreads();
    const int s2 = tid & 63, bq = tid >> 6;
    float o0 = 0.f, o1 = 0.f;
#pragma unroll
    for (int tt = 0; tt < 64; tt += 4) {
      const float m0 = Ms[(tt + 0) * 65 + s2];
      const float m1 = Ms[(tt + 1) * 65 + s2];
      const float m2 = Ms[(tt + 2) * 65 + s2];
      const float m3 = Ms[(tt + 3) * 65 + s2];
      float4 c0 = *reinterpret_cast<const float4*>(&Cs[bq * 64 + tt]);
      float4 c1 = *reinterpret_cast<const float4*>(&Cs[(bq + 4) * 64 + tt]);
      o0 = fmaf(m3, c0.w, fmaf(m2, c0.z, fmaf(m1, c0.y, fmaf(m0, c0.x, o0))));
      o1 = fmaf(m3, c1.w, fmaf(m2, c1.z, fmaf(m1, c1.y, fmaf(m0, c1.x, o1))));
    }
    float n0 = o0, n1 = o1;
#pragma unroll
    for (int off = 32; off > 0; off >>= 1) {
      n0 += __shfl_xor(n0, off);
      n1 += __shfl_xor(n1, off);
    }
    const float r0 = 1.0f / n0, r1 = 1.0f / n1;
    const size_t ob = ((size_t)br * HW + h * 64 + w) * 512;
    on[ob + (size_t)bq * 64 + s2] = o0 * r0;
    on[ob + (size_t)(bq + 4) * 64 + s2] = o1 * r1;
  }
}

// K4: out[brb][c][hw] = sum_s on[br][hw][b][s] * wl[c][s]  (MFMA role-swap)
__global__ __launch_bounds__(256) void out_kernel(const float* __restrict__ on,
                                                  const ushort* __restrict__ wlhi,
                                                  const ushort* __restrict__ wllo,
                                                  float* __restrict__ out) {
  __shared__ float Os[128 * 68];  // [hw_local][s] pad 68
  const int hwt = blockIdx.x;     // 32 tiles of 128 hw
  const int brb = blockIdx.y;     // 0..23
  const int br = brb >> 3, b = brb & 7;
  const int hw0 = hwt * 128;
  const int tid = threadIdx.x;
  const int l = tid & 63;
  const int wv = tid >> 6;        // wave 0..3 -> hw strip of 32
  const int l15 = l & 15;
  const int kgrp = l >> 4;

  {
    const int row = tid >> 4;
    const int s4 = (tid & 15) * 4;
#pragma unroll
    for (int it = 0; it < 8; ++it) {
      const int r = row + it * 16;
      *reinterpret_cast<float4*>(&Os[r * 68 + s4]) =
          *reinterpret_cast<const float4*>(&on[((size_t)(br * HW + hw0 + r) * 8 + b) * 64 + s4]);
    }
  }
  __syncthreads();

  short8 onh[2][2], onl[2][2];
#pragma unroll
  for (int nf = 0; nf < 2; ++nf)
#pragma unroll
    for (int ks = 0; ks < 2; ++ks) {
      const int row = wv * 32 + nf * 16 + l15;
      const float* p = &Os[row * 68 + ks * 32 + kgrp * 8];
      ushort th[8], tl[8];
#pragma unroll
      for (int i = 0; i < 8; ++i) {
        float r;
        th[i] = trunc_bf(p[i], &r);
        tl[i] = rne_bf(r);
      }
      onh[nf][ks] = *reinterpret_cast<const short8*>(th);
      onl[nf][ks] = *reinterpret_cast<const short8*>(tl);
    }

  for (int mf = 0; mf < 32; ++mf) {
    f32x4 acc[2] = {};
#pragma unroll
    for (int ks = 0; ks < 2; ++ks) {
      const size_t woff = (size_t)(mf * 16 + l15) * 64 + ks * 32 + kgrp * 8;
      const short8 wh8 = *reinterpret_cast<const short8*>(&wlhi[woff]);
      const short8 wl8 = *reinterpret_cast<const short8*>(&wllo[woff]);
#pragma unroll
      for (int nf = 0; nf < 2; ++nf) {
        acc[nf] = __builtin_amdgcn_mfma_f32_16x16x32_bf16(wh8, onh[nf][ks], acc[nf], 0, 0, 0);
        acc[nf] = __builtin_amdgcn_mfma_f32_16x16x32_bf16(wh8, onl[nf][ks], acc[nf], 0, 0, 0);
        acc[nf] = __builtin_amdgcn_mfma_f32_16x16x32_bf16(wl8, onh[nf][ks], acc[nf], 0, 0, 0);
      }
    }
#pragma unroll
    for (int nf = 0; nf < 2; ++nf)
#pragma unroll
      for (int r = 0; r < 4; ++r) {
        const int cc = mf * 16 + kgrp * 4 + r;
        out[(size_t)(brb * 512 + cc) * HW + hw0 + wv * 32 + nf * 16 + l15] = acc[nf][r];
      }
  }
}

extern "C" void kernel_launch(void* const* d_in, const int* in_sizes, int n_in,
                              void* d_out, int out_size, void* d_ws, size_t ws_size,
                              hipStream_t stream) {
  const float* q  = (const float*)d_in[0];
  const float* k  = (const float*)d_in[1];
  const float* v  = (const float*)d_in[2];
  const float* Wq = (const float*)d_in[3];
  const float* Wk = (const float*)d_in[4];
  const float* Wv = (const float*)d_in[5];
  const float* Wl = (const float*)d_in[6];
  float* out = (float*)d_out;

  float* ap = (float*)d_ws;                         // 3*HW*B*S floats = 25.2 MB
  float* rD = ap + (size_t)3 * HW * 512;            // 3*64*64*64 floats = 3.1 MB
  float* on = rD + (size_t)3 * 64 * 64 * 64;        // 3*HW*B*S floats = 25.2 MB
  ushort* whi  = (ushort*)rD;                       // 192 KB, consumed before denom overwrites rD
  ushort* wmid = whi + (size_t)3 * SDIM * CCH;
  ushort* wlo  = wmid + (size_t)3 * SDIM * CCH;
  ushort* wlhi = (ushort*)(on + (size_t)3 * HW * 512);  // 64 KB, after on
  ushort* wllo = wlhi + (size_t)SDIM * CCH;             // 64 KB

  prep_kernel<<<dim3(32, 4), 256, 0, stream>>>(Wq, Wk, Wv, Wl, whi, wmid, wlo, wlhi, wllo);
  proj_mfma_kernel<<<dim3(32, 8, 3), 256, 0, stream>>>(q, k, v, whi, wmid, wlo, ap);
  denom_kernel<<<dim3(64, 3, 4), 512, 0, stream>>>(ap, rD);
  attn_kernel<<<dim3(8, 64, 3), 256, 0, stream>>>(ap, rD, on);
  out_kernel<<<dim3(32, 24), 256, 0, stream>>>(on, wlhi, wllo, out);
}

// Round 17
// 250.846 us; speedup vs baseline: 1.3126x; 1.1016x over previous
//
#include <hip/hip_runtime.h>
#include <hip/hip_bf16.h>

#define HW 4096
#define CCH 512
#define SDIM 64
#define BDIM 8

typedef __attribute__((ext_vector_type(8))) short short8;
typedef __attribute__((ext_vector_type(4))) float f32x4;

static __device__ __forceinline__ ushort f2bf(float f) {
  __hip_bfloat16 h = __float2bfloat16(f);  // RNE (cold paths only)
  return *reinterpret_cast<ushort*>(&h);
}
static __device__ __forceinline__ float bf2f(ushort u) {
  union { unsigned int u32; float f; } c;
  c.u32 = ((unsigned int)u) << 16;
  return c.f;
}
// cheap exact split: hi = truncated top-16 bits (exact subtraction), rem returned
static __device__ __forceinline__ ushort trunc_bf(float f, float* rem) {
  union { float f; unsigned int u; } a; a.f = f;
  union { float f; unsigned int u; } h; h.u = a.u & 0xFFFF0000u;
  *rem = f - h.f;                 // exact
  return (ushort)(a.u >> 16);
}
static __device__ __forceinline__ ushort rne_bf(float f) {
  union { float f; unsigned int u; } a; a.f = f;
  return (ushort)((a.u + 0x8000u) >> 16);
}
// async global->LDS DMA: each lane contributes 16B; dest = uniform base + lane*16
static __device__ __forceinline__ void gll16(const void* g, void* lds_base) {
  __builtin_amdgcn_global_load_lds(
      (const __attribute__((address_space(1))) unsigned int*)g,
      (__attribute__((address_space(3))) unsigned int*)lds_base, 16, 0, 0);
}

// K0: split Wq/Wk/Wv into bf16 hi/mid/lo triples [br][s][c]; Wl into hi/lo [c][s]
__global__ __launch_bounds__(256) void prep_kernel(const float* __restrict__ Wq,
                                                   const float* __restrict__ Wk,
                                                   const float* __restrict__ Wv,
                                                   const float* __restrict__ Wl,
                                                   ushort* __restrict__ whi,
                                                   ushort* __restrict__ wmid,
                                                   ushort* __restrict__ wlo,
                                                   ushort* __restrict__ wlhi,
                                                   ushort* __restrict__ wllo) {
  const int idx = blockIdx.x * 1024 + threadIdx.x * 4;
  if (blockIdx.y == 3) {  // Wl -> hi/lo
    float4 f = *reinterpret_cast<const float4*>(&Wl[idx]);
    ushort4 h, l;
    float r;
    h.x = trunc_bf(f.x, &r); l.x = rne_bf(r);
    h.y = trunc_bf(f.y, &r); l.y = rne_bf(r);
    h.z = trunc_bf(f.z, &r); l.z = rne_bf(r);
    h.w = trunc_bf(f.w, &r); l.w = rne_bf(r);
    *reinterpret_cast<ushort4*>(&wlhi[idx]) = h;
    *reinterpret_cast<ushort4*>(&wllo[idx]) = l;
    return;
  }
  const float* W = blockIdx.y == 0 ? Wq : (blockIdx.y == 1 ? Wk : Wv);
  float4 f = *reinterpret_cast<const float4*>(&W[idx]);
  ushort4 h, m, l;
  float r, r2;
  h.x = f2bf(f.x); r = f.x - bf2f(h.x); m.x = f2bf(r); r2 = r - bf2f(m.x); l.x = f2bf(r2);
  h.y = f2bf(f.y); r = f.y - bf2f(h.y); m.y = f2bf(r); r2 = r - bf2f(m.y); l.y = f2bf(r2);
  h.z = f2bf(f.z); r = f.z - bf2f(h.z); m.z = f2bf(r); r2 = r - bf2f(m.z); l.z = f2bf(r2);
  h.w = f2bf(f.w); r = f.w - bf2f(h.w); m.w = f2bf(r); r2 = r - bf2f(m.w); l.w = f2bf(r2);
  const size_t o = (size_t)blockIdx.y * (SDIM * CCH) + idx;
  *reinterpret_cast<ushort4*>(&whi[o])  = h;
  *reinterpret_cast<ushort4*>(&wmid[o]) = m;
  *reinterpret_cast<ushort4*>(&wlo[o])  = l;
}

// K1: 3-way-split bf16 MFMA projection, Ootomo two-accumulator, M=128.
//   BOTH x and weights pipelined through LDS via gll16 DMA (zero VMEM register
//   loads in the loop -> hand-placed vmcnt(7) is the ONLY vmem wait; weight L2
//   latency hides one chunk ahead). Bank swizzles realized by pre-swizzling the
//   per-lane GLOBAL source (DMA LDS dest is linear): x: hw ^= ((c>>3)&1)<<4
//   (r13's verified conflict-free pattern); w: 16B-block j ^= (row>>1)&3.
//   ap[br][hw][b][s] = sum_c x_br[b][c][hw] * w_br[s][c]
__global__ __launch_bounds__(256) void proj_mfma_kernel(const float* __restrict__ q,
                                                        const float* __restrict__ k,
                                                        const float* __restrict__ v,
                                                        const ushort* __restrict__ whi,
                                                        const ushort* __restrict__ wmid,
                                                        const ushort* __restrict__ wlo,
                                                        float* __restrict__ ap) {
  __shared__ float Xs[2][32 * 128];        // 32 KB
  __shared__ ushort Ws[2][3][64 * 32];     // 24 KB
  const int mt = blockIdx.x;   // hw tile of 128
  const int b = blockIdx.y;
  const int br = blockIdx.z;
  const float* x = br == 0 ? q : (br == 1 ? k : v);
  const ushort* wsrc[3] = {whi + (size_t)br * SDIM * CCH,
                           wmid + (size_t)br * SDIM * CCH,
                           wlo + (size_t)br * SDIM * CCH};
  float* apo = ap + (size_t)br * HW * 512;
  const int hw0 = mt * 128;
  const int tid = threadIdx.x;
  const int l = tid & 63;
  const int wid = tid >> 6;
  const int wstrip = wid * 32;         // wave's 32-row m-strip
  const int row16 = l & 15;
  const int kgrp = l >> 4;
  const float* xcol = x + (size_t)b * CCH * HW + hw0;
  const int rbase = 8 * wid;           // wave stages x rows [8w, 8w+8)
  const int rsub = l >> 5;             // lanes 0-31 -> +0, 32-63 -> +1
  // w staging: wave stages rows [16w,16w+16) of each level; lane covers
  // (row_local = l>>2, block j' = l&3); global block j = j' ^ ((l>>3)&3)
  const int wrow = wid * 16 + (l >> 2);
  const int wblk = (l & 3) ^ ((l >> 3) & 3);
  // compute-side indices
  const int jp = kgrp ^ ((row16 >> 1) & 3);        // swizzled w block
  const int xswz = (kgrp & 1) << 4;                // x hw-bit-4 swizzle

  f32x4 acc_hi[2][4] = {};
  f32x4 acc_co[2][4] = {};

#define STAGE(BUF, CI)                                                            \
  do {                                                                            \
    /* x: 4 DMAs, source pre-swizzled on hw bit 4 by (c>>3)&1 */                  \
    _Pragma("unroll") for (int j = 0; j < 4; ++j) {                               \
      const int r = rbase + 2 * j + rsub;                                         \
      const int hwsrc = (((l & 31) ^ ((((r) >> 3) & 1) << 2)) * 4);               \
      gll16(xcol + (size_t)((CI) * 32 + r) * HW + hwsrc,                          \
            &Xs[BUF][(rbase + 2 * j) * 128]);                                     \
    }                                                                             \
    /* w: 3 DMAs (one per level), block-swizzled source */                        \
    _Pragma("unroll") for (int lv = 0; lv < 3; ++lv)                              \
      gll16(wsrc[lv] + (size_t)wrow * CCH + (CI) * 32 + wblk * 8,                 \
            &Ws[BUF][lv][wid * 512]);                                             \
  } while (0)

  // prologue: stage chunk 0
  STAGE(0, 0);

  for (int ci = 0; ci < 16; ++ci) {
    __builtin_amdgcn_sched_barrier(0);
    if (ci < 15) {
      STAGE((ci + 1) & 1, ci + 1);
      __builtin_amdgcn_sched_barrier(0);
      asm volatile("s_waitcnt vmcnt(7)" ::: "memory");  // chunk-ci DMAs done; ci+1 in flight
    } else {
      asm volatile("s_waitcnt vmcnt(0)" ::: "memory");
    }
    __builtin_amdgcn_sched_barrier(0);
    __builtin_amdgcn_s_barrier();      // all waves' chunk-ci data landed
    __builtin_amdgcn_sched_barrier(0);

    // weight fragments from LDS (2-way bank alias = free)
    short8 bh[4], bm[4], bl[4];
#pragma unroll
    for (int nf = 0; nf < 4; ++nf) {
      const int woff = (nf * 16 + row16) * 32 + jp * 8;
      bh[nf] = *reinterpret_cast<const short8*>(&Ws[ci & 1][0][woff]);
      bm[nf] = *reinterpret_cast<const short8*>(&Ws[ci & 1][1][woff]);
      bl[nf] = *reinterpret_cast<const short8*>(&Ws[ci & 1][2][woff]);
    }

    const float* lw = &Xs[ci & 1][0];
#pragma unroll
    for (int mf = 0; mf < 2; ++mf) {
      const int rowA = (wstrip + mf * 16 + row16) ^ xswz;
      short8 ah, am, al;
      {
        ushort th[8], tm[8], tl[8];
#pragma unroll
        for (int i = 0; i < 8; ++i) {
          const float f = lw[(kgrp * 8 + i) * 128 + rowA];
          float r, r2;
          th[i] = trunc_bf(f, &r);     // exact
          tm[i] = trunc_bf(r, &r2);    // exact
          tl[i] = rne_bf(r2);          // only rounding: eps <= 2^-25 |x|
        }
        ah = *reinterpret_cast<const short8*>(th);
        am = *reinterpret_cast<const short8*>(tm);
        al = *reinterpret_cast<const short8*>(tl);
      }
#pragma unroll
      for (int nf = 0; nf < 4; ++nf) {
        acc_hi[mf][nf] = __builtin_amdgcn_mfma_f32_16x16x32_bf16(ah, bh[nf], acc_hi[mf][nf], 0, 0, 0);
        acc_co[mf][nf] = __builtin_amdgcn_mfma_f32_16x16x32_bf16(ah, bm[nf], acc_co[mf][nf], 0, 0, 0);
        acc_co[mf][nf] = __builtin_amdgcn_mfma_f32_16x16x32_bf16(am, bh[nf], acc_co[mf][nf], 0, 0, 0);
        acc_co[mf][nf] = __builtin_amdgcn_mfma_f32_16x16x32_bf16(am, bm[nf], acc_co[mf][nf], 0, 0, 0);
        acc_co[mf][nf] = __builtin_amdgcn_mfma_f32_16x16x32_bf16(ah, bl[nf], acc_co[mf][nf], 0, 0, 0);
        acc_co[mf][nf] = __builtin_amdgcn_mfma_f32_16x16x32_bf16(al, bh[nf], acc_co[mf][nf], 0, 0, 0);
        acc_co[mf][nf] = __builtin_amdgcn_mfma_f32_16x16x32_bf16(am, bl[nf], acc_co[mf][nf], 0, 0, 0);
        acc_co[mf][nf] = __builtin_amdgcn_mfma_f32_16x16x32_bf16(al, bm[nf], acc_co[mf][nf], 0, 0, 0);
      }
    }
    __builtin_amdgcn_sched_barrier(0);
    __builtin_amdgcn_s_barrier();      // all waves done reading buf[ci&1]
    __builtin_amdgcn_sched_barrier(0);
  }
#undef STAGE

#pragma unroll
  for (int mf = 0; mf < 2; ++mf)
#pragma unroll
    for (int nf = 0; nf < 4; ++nf)
#pragma unroll
      for (int r = 0; r < 4; ++r) {
        const int m = hw0 + wstrip + mf * 16 + kgrp * 4 + r;
        apo[(size_t)m * 512 + b * 64 + nf * 16 + row16] = acc_hi[mf][nf][r] + acc_co[mf][nf][r];
      }
}

// K2: rD[br][h][s][t] = 1 / sum_w exp( sum_b A[h,w,b,s]*B[h,w,b,t] )
__global__ __launch_bounds__(512) void denom_kernel(const float* __restrict__ ap,
                                                    float* __restrict__ rD) {
  __shared__ float As[8 * 16];   // [b][s_local]
  __shared__ float Bs[8 * 64];   // [b][t]
  const int h = blockIdx.x, br = blockIdx.y, sq = blockIdx.z;
  const float* A  = ap + ((size_t)br * HW + (size_t)h * 64) * (BDIM * SDIM);
  const float* Bp = ap + ((size_t)((br + 1) % 3) * HW + (size_t)h * 64) * (BDIM * SDIM);
  const int tid = threadIdx.x;
  const int t = tid & 63;
  const int sg = tid >> 6;  // 0..7, each covers 2 s
  float D[2] = {};
  for (int w = 0; w < 64; ++w) {
    __syncthreads();
    if (tid < 128) As[tid] = A[w * 512 + (tid >> 4) * 64 + sq * 16 + (tid & 15)];
    Bs[tid] = Bp[w * 512 + tid];
    __syncthreads();
    float bv[8];
#pragma unroll
    for (int b = 0; b < 8; ++b) bv[b] = Bs[b * 64 + t];
#pragma unroll
    for (int j = 0; j < 2; ++j) {
      const int sl = sg * 2 + j;
      float m = 0.f;
#pragma unroll
      for (int b = 0; b < 8; ++b) m = fmaf(As[b * 16 + sl], bv[b], m);
      D[j] += __expf(m);
    }
  }
#pragma unroll
  for (int j = 0; j < 2; ++j)
    rD[((size_t)(br * 64 + h) * 64 + sq * 16 + sg * 2 + j) * 64 + t] = 1.0f / D[j];
}

// K3: on[br][hw][b][s] = o[s][b]/N[b], o = mtilde * C^T  (Ms transposed [t][s])
__global__ __launch_bounds__(256) void attn_kernel(const float* __restrict__ ap,
                                                   const float* __restrict__ rD,
                                                   float* __restrict__ on) {
  __shared__ float As[8 * 64], Bs[8 * 64], Cs[8 * 64];
  __shared__ float Ms[64 * 65];  // [t][s] padded 65
  const int wc = blockIdx.x, h = blockIdx.y, br = blockIdx.z;
  const float* A  = ap + ((size_t)br * HW + h * 64) * 512;
  const float* Bp = ap + ((size_t)((br + 1) % 3) * HW + h * 64) * 512;
  const float* Cp = ap + ((size_t)((br + 2) % 3) * HW + h * 64) * 512;
  const float* rDp = rD + (size_t)(br * 64 + h) * 4096;  // [s][t]
  const int tid = threadIdx.x;
  for (int w = wc * 8; w < wc * 8 + 8; ++w) {
    __syncthreads();
#pragma unroll
    for (int it = 0; it < 2; ++it) {
      int idx = it * 256 + tid;
      As[idx] = A[w * 512 + idx];
      Bs[idx] = Bp[w * 512 + idx];
      Cs[idx] = Cp[w * 512 + idx];
    }
    __syncthreads();
    {
      const int t = tid & 63, sg = tid >> 6;
      float bv[8];
#pragma unroll
      for (int b = 0; b < 8; ++b) bv[b] = Bs[b * 64 + t];
#pragma unroll
      for (int j = 0; j < 16; ++j) {
        int s = sg * 16 + j;
        float m = 0.f;
#pragma unroll
        for (int b = 0; b < 8; ++b) m = fmaf(As[b * 64 + s], bv[b], m);
        Ms[t * 65 + s] = __expf(m) * rDp[s * 64 + t];   // transposed store
      }
    }
    __syncthreads();
    const int s2 = tid & 63, bq = tid >> 6;
    float o0 = 0.f, o1 = 0.f;
#pragma unroll
    for (int tt = 0; tt < 64; tt += 4) {
      const float m0 = Ms[(tt + 0) * 65 + s2];
      const float m1 = Ms[(tt + 1) * 65 + s2];
      const float m2 = Ms[(tt + 2) * 65 + s2];
      const float m3 = Ms[(tt + 3) * 65 + s2];
      float4 c0 = *reinterpret_cast<const float4*>(&Cs[bq * 64 + tt]);
      float4 c1 = *reinterpret_cast<const float4*>(&Cs[(bq + 4) * 64 + tt]);
      o0 = fmaf(m3, c0.w, fmaf(m2, c0.z, fmaf(m1, c0.y, fmaf(m0, c0.x, o0))));
      o1 = fmaf(m3, c1.w, fmaf(m2, c1.z, fmaf(m1, c1.y, fmaf(m0, c1.x, o1))));
    }
    float n0 = o0, n1 = o1;
#pragma unroll
    for (int off = 32; off > 0; off >>= 1) {
      n0 += __shfl_xor(n0, off);
      n1 += __shfl_xor(n1, off);
    }
    const float r0 = 1.0f / n0, r1 = 1.0f / n1;
    const size_t ob = ((size_t)br * HW + h * 64 + w) * 512;
    on[ob + (size_t)bq * 64 + s2] = o0 * r0;
    on[ob + (size_t)(bq + 4) * 64 + s2] = o1 * r1;
  }
}

// K4: out[brb][c][hw] = sum_s on[br][hw][b][s] * wl[c][s]  (MFMA role-swap)
__global__ __launch_bounds__(256) void out_kernel(const float* __restrict__ on,
                                                  const ushort* __restrict__ wlhi,
                                                  const ushort* __restrict__ wllo,
                                                  float* __restrict__ out) {
  __shared__ float Os[128 * 68];  // [hw_local][s] pad 68
  const int hwt = blockIdx.x;     // 32 tiles of 128 hw
  const int brb = blockIdx.y;     // 0..23
  const int br = brb >> 3, b = brb & 7;
  const int hw0 = hwt * 128;
  const int tid = threadIdx.x;
  const int l = tid & 63;
  const int wv = tid >> 6;        // wave 0..3 -> hw strip of 32
  const int l15 = l & 15;
  const int kgrp = l >> 4;

  {
    const int row = tid >> 4;
    const int s4 = (tid & 15) * 4;
#pragma unroll
    for (int it = 0; it < 8; ++it) {
      const int r = row + it * 16;
      *reinterpret_cast<float4*>(&Os[r * 68 + s4]) =
          *reinterpret_cast<const float4*>(&on[((size_t)(br * HW + hw0 + r) * 8 + b) * 64 + s4]);
    }
  }
  __syncthreads();

  short8 onh[2][2], onl[2][2];
#pragma unroll
  for (int nf = 0; nf < 2; ++nf)
#pragma unroll
    for (int ks = 0; ks < 2; ++ks) {
      const int row = wv * 32 + nf * 16 + l15;
      const float* p = &Os[row * 68 + ks * 32 + kgrp * 8];
      ushort th[8], tl[8];
#pragma unroll
      for (int i = 0; i < 8; ++i) {
        float r;
        th[i] = trunc_bf(p[i], &r);
        tl[i] = rne_bf(r);
      }
      onh[nf][ks] = *reinterpret_cast<const short8*>(th);
      onl[nf][ks] = *reinterpret_cast<const short8*>(tl);
    }

  for (int mf = 0; mf < 32; ++mf) {
    f32x4 acc[2] = {};
#pragma unroll
    for (int ks = 0; ks < 2; ++ks) {
      const size_t woff = (size_t)(mf * 16 + l15) * 64 + ks * 32 + kgrp * 8;
      const short8 wh8 = *reinterpret_cast<const short8*>(&wlhi[woff]);
      const short8 wl8 = *reinterpret_cast<const short8*>(&wllo[woff]);
#pragma unroll
      for (int nf = 0; nf < 2; ++nf) {
        acc[nf] = __builtin_amdgcn_mfma_f32_16x16x32_bf16(wh8, onh[nf][ks], acc[nf], 0, 0, 0);
        acc[nf] = __builtin_amdgcn_mfma_f32_16x16x32_bf16(wh8, onl[nf][ks], acc[nf], 0, 0, 0);
        acc[nf] = __builtin_amdgcn_mfma_f32_16x16x32_bf16(wl8, onh[nf][ks], acc[nf], 0, 0, 0);
      }
    }
#pragma unroll
    for (int nf = 0; nf < 2; ++nf)
#pragma unroll
      for (int r = 0; r < 4; ++r) {
        const int cc = mf * 16 + kgrp * 4 + r;
        out[(size_t)(brb * 512 + cc) * HW + hw0 + wv * 32 + nf * 16 + l15] = acc[nf][r];
      }
  }
}

extern "C" void kernel_launch(void* const* d_in, const int* in_sizes, int n_in,
                              void* d_out, int out_size, void* d_ws, size_t ws_size,
                              hipStream_t stream) {
  const float* q  = (const float*)d_in[0];
  const float* k  = (const float*)d_in[1];
  const float* v  = (const float*)d_in[2];
  const float* Wq = (const float*)d_in[3];
  const float* Wk = (const float*)d_in[4];
  const float* Wv = (const float*)d_in[5];
  const float* Wl = (const float*)d_in[6];
  float* out = (float*)d_out;

  float* ap = (float*)d_ws;                         // 3*HW*B*S floats = 25.2 MB
  float* rD = ap + (size_t)3 * HW * 512;            // 3*64*64*64 floats = 3.1 MB
  float* on = rD + (size_t)3 * 64 * 64 * 64;        // 3*HW*B*S floats = 25.2 MB
  ushort* whi  = (ushort*)rD;                       // 192 KB, consumed before denom overwrites rD
  ushort* wmid = whi + (size_t)3 * SDIM * CCH;
  ushort* wlo  = wmid + (size_t)3 * SDIM * CCH;
  ushort* wlhi = (ushort*)(on + (size_t)3 * HW * 512);  // 64 KB, after on
  ushort* wllo = wlhi + (size_t)SDIM * CCH;             // 64 KB

  prep_kernel<<<dim3(32, 4), 256, 0, stream>>>(Wq, Wk, Wv, Wl, whi, wmid, wlo, wlhi, wllo);
  proj_mfma_kernel<<<dim3(32, 8, 3), 256, 0, stream>>>(q, k, v, whi, wmid, wlo, ap);
  denom_kernel<<<dim3(64, 3, 4), 512, 0, stream>>>(ap, rD);
  attn_kernel<<<dim3(8, 64, 3), 256, 0, stream>>>(ap, rD, on);
  out_kernel<<<dim3(32, 24), 256, 0, stream>>>(on, wlhi, wllo, out);
}

// Round 18
// 239.369 us; speedup vs baseline: 1.3756x; 1.0479x over previous
//
#include <hip/hip_runtime.h>
#include <hip/hip_bf16.h>

#define HW 4096
#define CCH 512
#define SDIM 64
#define BDIM 8

typedef __attribute__((ext_vector_type(8))) short short8;
typedef __attribute__((ext_vector_type(4))) float f32x4;

static __device__ __forceinline__ ushort f2bf(float f) {
  __hip_bfloat16 h = __float2bfloat16(f);  // RNE (cold paths only)
  return *reinterpret_cast<ushort*>(&h);
}
static __device__ __forceinline__ float bf2f(ushort u) {
  union { unsigned int u32; float f; } c;
  c.u32 = ((unsigned int)u) << 16;
  return c.f;
}
// cheap exact split: hi = truncated top-16 bits (exact subtraction), rem returned
static __device__ __forceinline__ ushort trunc_bf(float f, float* rem) {
  union { float f; unsigned int u; } a; a.f = f;
  union { float f; unsigned int u; } h; h.u = a.u & 0xFFFF0000u;
  *rem = f - h.f;                 // exact
  return (ushort)(a.u >> 16);
}
static __device__ __forceinline__ ushort rne_bf(float f) {
  union { float f; unsigned int u; } a; a.f = f;
  return (ushort)((a.u + 0x8000u) >> 16);
}
// async global->LDS DMA: each lane contributes 16B; dest = uniform base + lane*16
static __device__ __forceinline__ void gll16(const void* g, void* lds_base) {
  __builtin_amdgcn_global_load_lds(
      (const __attribute__((address_space(1))) unsigned int*)g,
      (__attribute__((address_space(3))) unsigned int*)lds_base, 16, 0, 0);
}

// K0: split Wq/Wk/Wv into bf16 hi/mid/lo triples [br][s][c]; Wl into hi/lo [c][s]
__global__ __launch_bounds__(256) void prep_kernel(const float* __restrict__ Wq,
                                                   const float* __restrict__ Wk,
                                                   const float* __restrict__ Wv,
                                                   const float* __restrict__ Wl,
                                                   ushort* __restrict__ whi,
                                                   ushort* __restrict__ wmid,
                                                   ushort* __restrict__ wlo,
                                                   ushort* __restrict__ wlhi,
                                                   ushort* __restrict__ wllo) {
  const int idx = blockIdx.x * 1024 + threadIdx.x * 4;
  if (blockIdx.y == 3) {  // Wl -> hi/lo
    float4 f = *reinterpret_cast<const float4*>(&Wl[idx]);
    ushort4 h, l;
    float r;
    h.x = trunc_bf(f.x, &r); l.x = rne_bf(r);
    h.y = trunc_bf(f.y, &r); l.y = rne_bf(r);
    h.z = trunc_bf(f.z, &r); l.z = rne_bf(r);
    h.w = trunc_bf(f.w, &r); l.w = rne_bf(r);
    *reinterpret_cast<ushort4*>(&wlhi[idx]) = h;
    *reinterpret_cast<ushort4*>(&wllo[idx]) = l;
    return;
  }
  const float* W = blockIdx.y == 0 ? Wq : (blockIdx.y == 1 ? Wk : Wv);
  float4 f = *reinterpret_cast<const float4*>(&W[idx]);
  ushort4 h, m, l;
  float r, r2;
  h.x = f2bf(f.x); r = f.x - bf2f(h.x); m.x = f2bf(r); r2 = r - bf2f(m.x); l.x = f2bf(r2);
  h.y = f2bf(f.y); r = f.y - bf2f(h.y); m.y = f2bf(r); r2 = r - bf2f(m.y); l.y = f2bf(r2);
  h.z = f2bf(f.z); r = f.z - bf2f(h.z); m.z = f2bf(r); r2 = r - bf2f(m.z); l.z = f2bf(r2);
  h.w = f2bf(f.w); r = f.w - bf2f(h.w); m.w = f2bf(r); r2 = r - bf2f(m.w); l.w = f2bf(r2);
  const size_t o = (size_t)blockIdx.y * (SDIM * CCH) + idx;
  *reinterpret_cast<ushort4*>(&whi[o])  = h;
  *reinterpret_cast<ushort4*>(&wmid[o]) = m;
  *reinterpret_cast<ushort4*>(&wlo[o])  = l;
}

// K1: 3-way-split bf16 MFMA projection (unchanged from round 17)
__global__ __launch_bounds__(256) void proj_mfma_kernel(const float* __restrict__ q,
                                                        const float* __restrict__ k,
                                                        const float* __restrict__ v,
                                                        const ushort* __restrict__ whi,
                                                        const ushort* __restrict__ wmid,
                                                        const ushort* __restrict__ wlo,
                                                        float* __restrict__ ap) {
  __shared__ float Xs[2][32 * 128];        // 32 KB
  __shared__ ushort Ws[2][3][64 * 32];     // 24 KB
  const int mt = blockIdx.x;   // hw tile of 128
  const int b = blockIdx.y;
  const int br = blockIdx.z;
  const float* x = br == 0 ? q : (br == 1 ? k : v);
  const ushort* wsrc[3] = {whi + (size_t)br * SDIM * CCH,
                           wmid + (size_t)br * SDIM * CCH,
                           wlo + (size_t)br * SDIM * CCH};
  float* apo = ap + (size_t)br * HW * 512;
  const int hw0 = mt * 128;
  const int tid = threadIdx.x;
  const int l = tid & 63;
  const int wid = tid >> 6;
  const int wstrip = wid * 32;         // wave's 32-row m-strip
  const int row16 = l & 15;
  const int kgrp = l >> 4;
  const float* xcol = x + (size_t)b * CCH * HW + hw0;
  const int rbase = 8 * wid;           // wave stages x rows [8w, 8w+8)
  const int rsub = l >> 5;             // lanes 0-31 -> +0, 32-63 -> +1
  const int wrow = wid * 16 + (l >> 2);
  const int wblk = (l & 3) ^ ((l >> 3) & 3);
  const int jp = kgrp ^ ((row16 >> 1) & 3);        // swizzled w block
  const int xswz = (kgrp & 1) << 4;                // x hw-bit-4 swizzle

  f32x4 acc_hi[2][4] = {};
  f32x4 acc_co[2][4] = {};

#define STAGE(BUF, CI)                                                            \
  do {                                                                            \
    _Pragma("unroll") for (int j = 0; j < 4; ++j) {                               \
      const int r = rbase + 2 * j + rsub;                                         \
      const int hwsrc = (((l & 31) ^ ((((r) >> 3) & 1) << 2)) * 4);               \
      gll16(xcol + (size_t)((CI) * 32 + r) * HW + hwsrc,                          \
            &Xs[BUF][(rbase + 2 * j) * 128]);                                     \
    }                                                                             \
    _Pragma("unroll") for (int lv = 0; lv < 3; ++lv)                              \
      gll16(wsrc[lv] + (size_t)wrow * CCH + (CI) * 32 + wblk * 8,                 \
            &Ws[BUF][lv][wid * 512]);                                             \
  } while (0)

  STAGE(0, 0);

  for (int ci = 0; ci < 16; ++ci) {
    __builtin_amdgcn_sched_barrier(0);
    if (ci < 15) {
      STAGE((ci + 1) & 1, ci + 1);
      __builtin_amdgcn_sched_barrier(0);
      asm volatile("s_waitcnt vmcnt(7)" ::: "memory");
    } else {
      asm volatile("s_waitcnt vmcnt(0)" ::: "memory");
    }
    __builtin_amdgcn_sched_barrier(0);
    __builtin_amdgcn_s_barrier();
    __builtin_amdgcn_sched_barrier(0);

    short8 bh[4], bm[4], bl[4];
#pragma unroll
    for (int nf = 0; nf < 4; ++nf) {
      const int woff = (nf * 16 + row16) * 32 + jp * 8;
      bh[nf] = *reinterpret_cast<const short8*>(&Ws[ci & 1][0][woff]);
      bm[nf] = *reinterpret_cast<const short8*>(&Ws[ci & 1][1][woff]);
      bl[nf] = *reinterpret_cast<const short8*>(&Ws[ci & 1][2][woff]);
    }

    const float* lw = &Xs[ci & 1][0];
#pragma unroll
    for (int mf = 0; mf < 2; ++mf) {
      const int rowA = (wstrip + mf * 16 + row16) ^ xswz;
      short8 ah, am, al;
      {
        ushort th[8], tm[8], tl[8];
#pragma unroll
        for (int i = 0; i < 8; ++i) {
          const float f = lw[(kgrp * 8 + i) * 128 + rowA];
          float r, r2;
          th[i] = trunc_bf(f, &r);
          tm[i] = trunc_bf(r, &r2);
          tl[i] = rne_bf(r2);
        }
        ah = *reinterpret_cast<const short8*>(th);
        am = *reinterpret_cast<const short8*>(tm);
        al = *reinterpret_cast<const short8*>(tl);
      }
#pragma unroll
      for (int nf = 0; nf < 4; ++nf) {
        acc_hi[mf][nf] = __builtin_amdgcn_mfma_f32_16x16x32_bf16(ah, bh[nf], acc_hi[mf][nf], 0, 0, 0);
        acc_co[mf][nf] = __builtin_amdgcn_mfma_f32_16x16x32_bf16(ah, bm[nf], acc_co[mf][nf], 0, 0, 0);
        acc_co[mf][nf] = __builtin_amdgcn_mfma_f32_16x16x32_bf16(am, bh[nf], acc_co[mf][nf], 0, 0, 0);
        acc_co[mf][nf] = __builtin_amdgcn_mfma_f32_16x16x32_bf16(am, bm[nf], acc_co[mf][nf], 0, 0, 0);
        acc_co[mf][nf] = __builtin_amdgcn_mfma_f32_16x16x32_bf16(ah, bl[nf], acc_co[mf][nf], 0, 0, 0);
        acc_co[mf][nf] = __builtin_amdgcn_mfma_f32_16x16x32_bf16(al, bh[nf], acc_co[mf][nf], 0, 0, 0);
        acc_co[mf][nf] = __builtin_amdgcn_mfma_f32_16x16x32_bf16(am, bl[nf], acc_co[mf][nf], 0, 0, 0);
        acc_co[mf][nf] = __builtin_amdgcn_mfma_f32_16x16x32_bf16(al, bm[nf], acc_co[mf][nf], 0, 0, 0);
      }
    }
    __builtin_amdgcn_sched_barrier(0);
    __builtin_amdgcn_s_barrier();
    __builtin_amdgcn_sched_barrier(0);
  }
#undef STAGE

#pragma unroll
  for (int mf = 0; mf < 2; ++mf)
#pragma unroll
    for (int nf = 0; nf < 4; ++nf)
#pragma unroll
      for (int r = 0; r < 4; ++r) {
        const int m = hw0 + wstrip + mf * 16 + kgrp * 4 + r;
        apo[(size_t)m * 512 + b * 64 + nf * 16 + row16] = acc_hi[mf][nf][r] + acc_co[mf][nf][r];
      }
}

// K2: rD[br][h][s][t] = 1 / sum_w exp( sum_b A[h,w,b,s]*B[h,w,b,t] )  (unchanged)
__global__ __launch_bounds__(512) void denom_kernel(const float* __restrict__ ap,
                                                    float* __restrict__ rD) {
  __shared__ float As[8 * 16];   // [b][s_local]
  __shared__ float Bs[8 * 64];   // [b][t]
  const int h = blockIdx.x, br = blockIdx.y, sq = blockIdx.z;
  const float* A  = ap + ((size_t)br * HW + (size_t)h * 64) * (BDIM * SDIM);
  const float* Bp = ap + ((size_t)((br + 1) % 3) * HW + (size_t)h * 64) * (BDIM * SDIM);
  const int tid = threadIdx.x;
  const int t = tid & 63;
  const int sg = tid >> 6;  // 0..7, each covers 2 s
  float D[2] = {};
  for (int w = 0; w < 64; ++w) {
    __syncthreads();
    if (tid < 128) As[tid] = A[w * 512 + (tid >> 4) * 64 + sq * 16 + (tid & 15)];
    Bs[tid] = Bp[w * 512 + tid];
    __syncthreads();
    float bv[8];
#pragma unroll
    for (int b = 0; b < 8; ++b) bv[b] = Bs[b * 64 + t];
#pragma unroll
    for (int j = 0; j < 2; ++j) {
      const int sl = sg * 2 + j;
      float m = 0.f;
#pragma unroll
      for (int b = 0; b < 8; ++b) m = fmaf(As[b * 16 + sl], bv[b], m);
      D[j] += __expf(m);
    }
  }
#pragma unroll
  for (int j = 0; j < 2; ++j)
    rD[((size_t)(br * 64 + h) * 64 + sq * 16 + sg * 2 + j) * 64 + t] = 1.0f / D[j];
}

// K3: on[br][hw][b][s] = o[s][b]/N[b], o = mtilde * C^T
//   Restructured: rD preloaded into 16 regs (w-invariant); A/B/C staged via
//   gll16 DMA into a TRIPLE-buffered tile (wave i stages array i; per-wave
//   vmcnt(2) covers its own array, collective s_barrier implies all landed).
//   Zero VMEM register loads in the w-loop; 2 barriers per w.
__global__ __launch_bounds__(256) void attn_kernel(const float* __restrict__ ap,
                                                   const float* __restrict__ rD,
                                                   float* __restrict__ on) {
  __shared__ float Tile[3][3 * 512];   // [buf][arr*512 + idx]  (A,B,C)
  __shared__ float Ms[64 * 65];        // [t][s] padded 65
  const int wc = blockIdx.x, h = blockIdx.y, br = blockIdx.z;
  const float* A  = ap + ((size_t)br * HW + h * 64) * 512;
  const float* Bp = ap + ((size_t)((br + 1) % 3) * HW + h * 64) * 512;
  const float* Cp = ap + ((size_t)((br + 2) % 3) * HW + h * 64) * 512;
  const float* rDp = rD + (size_t)(br * 64 + h) * 4096;  // [s][t]
  const int tid = threadIdx.x;
  const int t = tid & 63;       // lane
  const int sg = tid >> 6;      // wave id 0..3
  const int w0 = wc * 8;

  // preload rD for this thread's 16 (s,t) cells — w-invariant
  float rdv[16];
#pragma unroll
  for (int j = 0; j < 16; ++j) rdv[j] = rDp[(sg * 16 + j) * 64 + t];

  const float* src = sg == 0 ? A : (sg == 1 ? Bp : Cp);

#define STAGE_T(BUF, W)                                                   \
  do {                                                                    \
    if (sg < 3) {                                                         \
      _Pragma("unroll") for (int j = 0; j < 2; ++j)                       \
        gll16(src + (size_t)(W) * 512 + j * 256 + t * 4,                  \
              &Tile[BUF][sg * 512 + j * 256]);                            \
    }                                                                     \
  } while (0)

  STAGE_T(0, w0);

  for (int wi = 0; wi < 8; ++wi) {
    __builtin_amdgcn_sched_barrier(0);
    if (wi < 7) {
      STAGE_T((wi + 1) % 3, w0 + wi + 1);
      __builtin_amdgcn_sched_barrier(0);
      asm volatile("s_waitcnt vmcnt(2)" ::: "memory");  // my tile-wi DMAs done
    } else {
      asm volatile("s_waitcnt vmcnt(0)" ::: "memory");
    }
    __builtin_amdgcn_sched_barrier(0);
    __builtin_amdgcn_s_barrier();        // all arrays of tile wi landed
    __builtin_amdgcn_sched_barrier(0);

    const float* Aw = &Tile[wi % 3][0];
    const float* Bw = &Tile[wi % 3][512];
    const float* Cw = &Tile[wi % 3][1024];
    {
      float bv[8];
#pragma unroll
      for (int b = 0; b < 8; ++b) bv[b] = Bw[b * 64 + t];
#pragma unroll
      for (int j = 0; j < 16; ++j) {
        const int s = sg * 16 + j;
        float m = 0.f;
#pragma unroll
        for (int b = 0; b < 8; ++b) m = fmaf(Aw[b * 64 + s], bv[b], m);
        Ms[t * 65 + s] = __expf(m) * rdv[j];   // transposed store
      }
    }
    __builtin_amdgcn_sched_barrier(0);
    __builtin_amdgcn_s_barrier();        // Ms ready
    __builtin_amdgcn_sched_barrier(0);

    float o0 = 0.f, o1 = 0.f;
#pragma unroll
    for (int tt = 0; tt < 64; tt += 4) {
      const float m0 = Ms[(tt + 0) * 65 + t];
      const float m1 = Ms[(tt + 1) * 65 + t];
      const float m2 = Ms[(tt + 2) * 65 + t];
      const float m3 = Ms[(tt + 3) * 65 + t];
      float4 c0 = *reinterpret_cast<const float4*>(&Cw[sg * 64 + tt]);
      float4 c1 = *reinterpret_cast<const float4*>(&Cw[(sg + 4) * 64 + tt]);
      o0 = fmaf(m3, c0.w, fmaf(m2, c0.z, fmaf(m1, c0.y, fmaf(m0, c0.x, o0))));
      o1 = fmaf(m3, c1.w, fmaf(m2, c1.z, fmaf(m1, c1.y, fmaf(m0, c1.x, o1))));
    }
    float n0 = o0, n1 = o1;
#pragma unroll
    for (int off = 32; off > 0; off >>= 1) {
      n0 += __shfl_xor(n0, off);
      n1 += __shfl_xor(n1, off);
    }
    const float r0 = 1.0f / n0, r1 = 1.0f / n1;
    const size_t ob = ((size_t)br * HW + h * 64 + w0 + wi) * 512;
    on[ob + (size_t)sg * 64 + t] = o0 * r0;
    on[ob + (size_t)(sg + 4) * 64 + t] = o1 * r1;
  }
#undef STAGE_T
}

// K4: out[brb][c][hw] = sum_s on[br][hw][b][s] * wl[c][s]  (MFMA role-swap, unchanged)
__global__ __launch_bounds__(256) void out_kernel(const float* __restrict__ on,
                                                  const ushort* __restrict__ wlhi,
                                                  const ushort* __restrict__ wllo,
                                                  float* __restrict__ out) {
  __shared__ float Os[128 * 68];  // [hw_local][s] pad 68
  const int hwt = blockIdx.x;     // 32 tiles of 128 hw
  const int brb = blockIdx.y;     // 0..23
  const int br = brb >> 3, b = brb & 7;
  const int hw0 = hwt * 128;
  const int tid = threadIdx.x;
  const int l = tid & 63;
  const int wv = tid >> 6;        // wave 0..3 -> hw strip of 32
  const int l15 = l & 15;
  const int kgrp = l >> 4;

  {
    const int row = tid >> 4;
    const int s4 = (tid & 15) * 4;
#pragma unroll
    for (int it = 0; it < 8; ++it) {
      const int r = row + it * 16;
      *reinterpret_cast<float4*>(&Os[r * 68 + s4]) =
          *reinterpret_cast<const float4*>(&on[((size_t)(br * HW + hw0 + r) * 8 + b) * 64 + s4]);
    }
  }
  __syncthreads();

  short8 onh[2][2], onl[2][2];
#pragma unroll
  for (int nf = 0; nf < 2; ++nf)
#pragma unroll
    for (int ks = 0; ks < 2; ++ks) {
      const int row = wv * 32 + nf * 16 + l15;
      const float* p = &Os[row * 68 + ks * 32 + kgrp * 8];
      ushort th[8], tl[8];
#pragma unroll
      for (int i = 0; i < 8; ++i) {
        float r;
        th[i] = trunc_bf(p[i], &r);
        tl[i] = rne_bf(r);
      }
      onh[nf][ks] = *reinterpret_cast<const short8*>(th);
      onl[nf][ks] = *reinterpret_cast<const short8*>(tl);
    }

  for (int mf = 0; mf < 32; ++mf) {
    f32x4 acc[2] = {};
#pragma unroll
    for (int ks = 0; ks < 2; ++ks) {
      const size_t woff = (size_t)(mf * 16 + l15) * 64 + ks * 32 + kgrp * 8;
      const short8 wh8 = *reinterpret_cast<const short8*>(&wlhi[woff]);
      const short8 wl8 = *reinterpret_cast<const short8*>(&wllo[woff]);
#pragma unroll
      for (int nf = 0; nf < 2; ++nf) {
        acc[nf] = __builtin_amdgcn_mfma_f32_16x16x32_bf16(wh8, onh[nf][ks], acc[nf], 0, 0, 0);
        acc[nf] = __builtin_amdgcn_mfma_f32_16x16x32_bf16(wh8, onl[nf][ks], acc[nf], 0, 0, 0);
        acc[nf] = __builtin_amdgcn_mfma_f32_16x16x32_bf16(wl8, onh[nf][ks], acc[nf], 0, 0, 0);
      }
    }
#pragma unroll
    for (int nf = 0; nf < 2; ++nf)
#pragma unroll
      for (int r = 0; r < 4; ++r) {
        const int cc = mf * 16 + kgrp * 4 + r;
        out[(size_t)(brb * 512 + cc) * HW + hw0 + wv * 32 + nf * 16 + l15] = acc[nf][r];
      }
  }
}

extern "C" void kernel_launch(void* const* d_in, const int* in_sizes, int n_in,
                              void* d_out, int out_size, void* d_ws, size_t ws_size,
                              hipStream_t stream) {
  const float* q  = (const float*)d_in[0];
  const float* k  = (const float*)d_in[1];
  const float* v  = (const float*)d_in[2];
  const float* Wq = (const float*)d_in[3];
  const float* Wk = (const float*)d_in[4];
  const float* Wv = (const float*)d_in[5];
  const float* Wl = (const float*)d_in[6];
  float* out = (float*)d_out;

  float* ap = (float*)d_ws;                         // 3*HW*B*S floats = 25.2 MB
  float* rD = ap + (size_t)3 * HW * 512;            // 3*64*64*64 floats = 3.1 MB
  float* on = rD + (size_t)3 * 64 * 64 * 64;        // 3*HW*B*S floats = 25.2 MB
  ushort* whi  = (ushort*)rD;                       // 192 KB, consumed before denom overwrites rD
  ushort* wmid = whi + (size_t)3 * SDIM * CCH;
  ushort* wlo  = wmid + (size_t)3 * SDIM * CCH;
  ushort* wlhi = (ushort*)(on + (size_t)3 * HW * 512);  // 64 KB, after on
  ushort* wllo = wlhi + (size_t)SDIM * CCH;             // 64 KB

  prep_kernel<<<dim3(32, 4), 256, 0, stream>>>(Wq, Wk, Wv, Wl, whi, wmid, wlo, wlhi, wllo);
  proj_mfma_kernel<<<dim3(32, 8, 3), 256, 0, stream>>>(q, k, v, whi, wmid, wlo, ap);
  denom_kernel<<<dim3(64, 3, 4), 512, 0, stream>>>(ap, rD);
  attn_kernel<<<dim3(8, 64, 3), 256, 0, stream>>>(ap, rD, on);
  out_kernel<<<dim3(32, 24), 256, 0, stream>>>(on, wlhi, wllo, out);
}